// Round 7
// baseline (6338.216 us; speedup 1.0000x reference)
//
#include <hip/hip_runtime.h>
#include <hip/hip_bf16.h>

// LSTM T=512 B=32 IN=H=1024 L=2. fp32 in/out, bf16 MFMA internally.
// Round 7: XCD-localized recurrence with L2(sc0) intra flags, packed-bf16 xg
// mailboxes, poll-storm-free workers. l0=XCD0, l1=XCD1, workers XCD2-7.

namespace {
constexpr int T_STEPS = 512;
constexpr int HID     = 1024;
constexpr int G4H     = 4096;
constexpr int BH      = 32 * HID;                    // 32768
constexpr size_t MEM_ELEMS = (size_t)T_STEPS * BH;   // 16,777,216

// ---- mesh workspace layout (bytes) ----
constexpr size_t OFF_WFHH = 0;                        // bf16 frags [2][32r][8w][32f][64][8]
constexpr size_t SZ_WF1   = (size_t)32 * 8 * 32 * 64 * 8 * 2;   // 8,388,608
constexpr size_t OFF_WFI0 = OFF_WFHH + 2 * SZ_WF1;
constexpr size_t OFF_WFI1 = OFF_WFI0 + SZ_WF1;
constexpr size_t OFF_BIAS = OFF_WFI1 + SZ_WF1;        // f32 [2][4096]
constexpr size_t OFF_H0L  = OFF_BIAS + 32768;         // bf16 ring [8][32][1024]
constexpr size_t OFF_H1L  = OFF_H0L + (size_t)8 * BH * 2;
constexpr size_t OFF_H0X  = OFF_H1L + (size_t)8 * BH * 2;              // bf16 [513][32][1024]
constexpr size_t OFF_XG0  = OFF_H0X + (size_t)(T_STEPS + 1) * BH * 2;  // pk [128][32r][512t][16B]
constexpr size_t OFF_XG1  = OFF_XG0 + (size_t)128 * 32 * 512 * 16;     // pk [16][32r][512t][16B]
constexpr size_t OFF_CTRL = OFF_XG1 + (size_t)16 * 32 * 512 * 16;
constexpr size_t SZ_CTRL  = 131072;                   // 32768 u32 words
constexpr size_t WS_MESH  = OFF_CTRL + SZ_CTRL;       // ~106.1 MB

// ctrl u32 word offsets
constexpr int CW_XCD  = 0;      // + xcd*16 : claim counters (agent)
constexpr int CW_CNT0 = 128;    // + r      : XG0 tickets (agent RMW)
constexpr int CW_CNT1 = 192;    // + r      : XG1 tickets (agent RMW)
constexpr int CW_L0P  = 256;    // l0 progress (agent)
constexpr int CW_L1P  = 272;    // l1 progress (agent)
constexpr int CW_IF0  = 512;    // + r*16   : intra flags L0 (sc0 / XCD0-L2)
constexpr int CW_IF1  = 1024;   // + r*16   : intra flags L1 (sc0 / XCD1-L2)
constexpr int CW_H0XF = 1536;   // + r*16   : h0 cross-XCD flags (agent)
constexpr int CW_XF1  = 4096;   // + slot*32 + r : xg1 flags, 16 slots (agent)
constexpr int CW_XF0  = 16384;  // + s*32 + r    : xg0 flags, absolute (agent)

// ---- tier-2 layout (round-1 proven) ----
constexpr size_t T2_W    = 0;
constexpr size_t T2_SZW  = (size_t)2 * G4H * 2048 * 2;
constexpr size_t T2_BIAS = T2_W + T2_SZW;
constexpr size_t T2_H0   = T2_BIAS + 32768;
constexpr size_t T2_H1   = T2_H0 + (size_t)2 * BH * 2;
constexpr size_t WS_STEP = T2_H1 + (size_t)2 * BH * 2;
}

typedef __attribute__((ext_vector_type(8))) short short8;
typedef __attribute__((ext_vector_type(4))) float f32x4;
typedef unsigned short u16;
typedef unsigned long long u64;

__device__ inline unsigned short f2bf(float x) {
  unsigned u = __builtin_bit_cast(unsigned, x);
  u += 0x7fffu + ((u >> 16) & 1u);          // RNE
  return (unsigned short)(u >> 16);
}
__device__ inline float sigm(float x) { return 1.0f / (1.0f + __expf(-x)); }

// agent-scope (L3) 16B load as 2x u64 atomic loads (proven r4)
__device__ inline short8 ld_sc16(const u16* p) {
  const u64* q = (const u64*)p;
  u64 q0 = __hip_atomic_load(q,     __ATOMIC_RELAXED, __HIP_MEMORY_SCOPE_AGENT);
  u64 q1 = __hip_atomic_load(q + 1, __ATOMIC_RELAXED, __HIP_MEMORY_SCOPE_AGENT);
  union { u64 u[2]; short8 s; } r; r.u[0] = q0; r.u[1] = q1; return r.s;
}
// L2-scope (sc0) helpers (mechanism validated r6: h mailbox was correct)
__device__ inline void st_u16_sc0(u16* p, unsigned v) {
  asm volatile("global_store_short %0, %1, off sc0" :: "v"(p), "v"(v) : "memory");
}
__device__ inline unsigned ld_flag_sc0(const unsigned* p) {
  unsigned v;
  asm volatile("global_load_dword %0, %1, off sc0\n\ts_waitcnt vmcnt(0)"
               : "=v"(v) : "v"(p) : "memory");
  return v;
}
__device__ inline void st_flag_sc0(unsigned* p, unsigned v) {
  asm volatile("global_store_dword %0, %1, off sc0" :: "v"(p), "v"(v) : "memory");
}

// ---------------- cvt: weight fragments + bias + initial h ----------------
__global__ void cvt_mesh(const float* __restrict__ Wih, const float* __restrict__ Whh,
                         const float* __restrict__ bih, const float* __restrict__ bhh,
                         const float* __restrict__ h0,
                         u16* __restrict__ WFHH, u16* __restrict__ WFI0, u16* __restrict__ WFI1,
                         float* __restrict__ bias, u16* __restrict__ H0L, u16* __restrict__ H1L) {
  size_t idx = (size_t)blockIdx.x * blockDim.x + threadIdx.x;
  size_t stride = (size_t)gridDim.x * blockDim.x;
  const size_t NFRAG = (size_t)4 * 524288;   // 4 arrays x 2^19 frags
  for (size_t fi = idx; fi < NFRAG; fi += stride) {
    int arr = (int)(fi >> 19);
    unsigned i = (unsigned)(fi & 524287u);
    int lane = i & 63, f = (i >> 6) & 31, w = (i >> 11) & 7, r = i >> 14;
    int nt = f >> 3, kc = f & 7, nhh = w & 1, kss = w >> 1;
    int l15 = lane & 15, lqq = lane >> 4;
    int nl = nhh * 64 + nt * 16 + l15;        // col within the 128-gate block
    int g = nl >> 5, uu = nl & 31;            // gate (i,f,g,o), unit-in-role
    int grow = g * 1024 + r * 32 + uu;        // global weight row
    int kb = kss * 256 + kc * 32 + lqq * 8;   // K offset
    const float* src = (arr == 0) ? Whh + (size_t)grow * 1024 + kb
                     : (arr == 1) ? Whh + (size_t)(4096 + grow) * 1024 + kb
                     : (arr == 2) ? Wih + (size_t)grow * 1024 + kb
                                  : Wih + (size_t)(4096 + grow) * 1024 + kb;
    u16* dst = ((arr == 0) ? WFHH : (arr == 1) ? (WFHH + 4194304) : (arr == 2) ? WFI0 : WFI1)
               + (size_t)i * 8;
    short8 o;
    #pragma unroll
    for (int e = 0; e < 8; ++e) o[e] = (short)f2bf(src[e]);
    *(short8*)dst = o;
  }
  for (size_t i = idx; i < 8192; i += stride) bias[i] = bih[i] + bhh[i];
  for (size_t i = idx; i < (size_t)BH; i += stride) {
    H0L[i] = f2bf(h0[i]);
    H1L[i] = f2bf(h0[BH + i]);
  }
}

// ---------------- persistent mesh kernel ----------------
__global__ __launch_bounds__(512, 2) void lstm_mesh(
    const float* __restrict__ X, const float* __restrict__ c0in,
    float* __restrict__ out,
    const u16* __restrict__ WFHH, const u16* __restrict__ WFI0, const u16* __restrict__ WFI1,
    const float* __restrict__ bias,
    u16* __restrict__ H0L, u16* __restrict__ H1L, u16* __restrict__ H0X,
    unsigned char* __restrict__ XG0pk, unsigned char* __restrict__ XG1pk,
    unsigned* __restrict__ ctrl)
{
  // 104 KiB static LDS -> exactly 1 block/CU -> 32 blocks per XCD, guaranteed.
  __shared__ float redf[13][2][4][256];
  const int tid = threadIdx.x;

  // ---- deterministic role claim via XCC_ID ----
  if (tid == 0) {
    unsigned xcd;
    asm volatile("s_getreg_b32 %0, hwreg(HW_REG_XCC_ID)" : "=s"(xcd));
    xcd &= 7u;
    unsigned rk = __hip_atomic_fetch_add(&ctrl[CW_XCD + xcd * 16], 1u,
                                         __ATOMIC_RELAXED, __HIP_MEMORY_SCOPE_AGENT);
    unsigned kind, role;
    if (xcd == 0u)      { kind = (rk < 32u) ? 0u : 4u; role = rk & 31u; }
    else if (xcd == 1u) { kind = (rk < 32u) ? 1u : 4u; role = rk & 31u; }
    else if (xcd <= 4u) { kind = 2u; role = rk & 31u; }
    else                { kind = 3u; role = rk & 31u; }
    redf[0][0][0][0] = __builtin_bit_cast(float, kind);
    redf[0][0][0][1] = __builtin_bit_cast(float, role);
  }
  __syncthreads();
  const unsigned kind = __builtin_bit_cast(unsigned, redf[0][0][0][0]);
  const int r = (int)__builtin_bit_cast(unsigned, redf[0][0][0][1]);
  __syncthreads();
  if (kind == 4u) return;

  const int lane = tid & 63, wid = tid >> 6;
  const int l15 = lane & 15, lq = lane >> 4;
  const int ks = wid >> 1;                // K-slice 0..3 (256 each)
  const int u = tid & 31, m2 = tid >> 5;  // epilogue cells (m2,u),(m2+16,u)
  const int col = r * 32 + u;
  const int lane16 = ((m2 >> 2) << 4) | (u & 15);
  const int reg = m2 & 3;

  // ---- weights into registers (32 x short8), K=1024 per role ----
  const u16* wsrc =
      (kind == 0u) ? WFHH + ((size_t)(0 * 32 + r) * 8 + wid) * 16384
    : (kind == 1u) ? WFHH + ((size_t)(1 * 32 + r) * 8 + wid) * 16384
    : (kind == 2u) ? WFI0 + ((size_t)r * 8 + wid) * 16384
                   : WFI1 + ((size_t)r * 8 + wid) * 16384;
  short8 wb[32];
  #pragma unroll
  for (int f = 0; f < 32; ++f)
    wb[f] = *(const short8*)(wsrc + ((size_t)f * 64 + lane) * 8);

  float bs[4];
  if (kind >= 2u) {
    #pragma unroll
    for (int g = 0; g < 4; ++g)
      bs[g] = bias[(kind == 3u ? 4096 : 0) + g * 1024 + col];
  }

#define MFMA_ALL(AARR)                                                        \
  _Pragma("unroll")                                                           \
  for (int kc = 0; kc < 8; ++kc) {                                            \
    _Pragma("unroll")                                                         \
    for (int nt = 0; nt < 4; ++nt) {                                          \
      acc0[nt] = __builtin_amdgcn_mfma_f32_16x16x32_bf16(AARR[kc], wb[nt*8+kc], acc0[nt], 0, 0, 0); \
      acc1[nt] = __builtin_amdgcn_mfma_f32_16x16x32_bf16(AARR[8+kc], wb[nt*8+kc], acc1[nt], 0, 0, 0); \
    }                                                                         \
  }

#define RED_WRITE()                                                           \
  _Pragma("unroll")                                                           \
  for (int nt = 0; nt < 4; ++nt) {                                            \
    *(f32x4*)&redf[wid][0][nt][lane * 4] = acc0[nt];                          \
    *(f32x4*)&redf[wid][1][nt][lane * 4] = acc1[nt];                          \
  }                                                                           \
  __syncthreads();

#define RED_READ(GS)                                                          \
  _Pragma("unroll")                                                           \
  for (int mt = 0; mt < 2; ++mt) {                                            \
    _Pragma("unroll")                                                         \
    for (int g = 0; g < 4; ++g) {                                             \
      const int nhh = g >> 1;                                                 \
      const int ntl = (g * 2 + (u >> 4)) & 3;                                 \
      float v = 0.f;                                                          \
      _Pragma("unroll")                                                       \
      for (int kq = 0; kq < 4; ++kq)                                          \
        v += redf[kq * 2 + nhh][mt][ntl][lane16 * 4 + reg];                   \
      GS[mt][g] = v;                                                          \
    }                                                                         \
  }

#define LOAD16_SC0(HB0, HB1)                                                  \
  asm volatile(                                                               \
    "global_load_dwordx4 %0,  %16, off sc0\n\t"                               \
    "global_load_dwordx4 %1,  %16, off offset:64 sc0\n\t"                     \
    "global_load_dwordx4 %2,  %16, off offset:128 sc0\n\t"                    \
    "global_load_dwordx4 %3,  %16, off offset:192 sc0\n\t"                    \
    "global_load_dwordx4 %4,  %16, off offset:256 sc0\n\t"                    \
    "global_load_dwordx4 %5,  %16, off offset:320 sc0\n\t"                    \
    "global_load_dwordx4 %6,  %16, off offset:384 sc0\n\t"                    \
    "global_load_dwordx4 %7,  %16, off offset:448 sc0\n\t"                    \
    "global_load_dwordx4 %8,  %17, off sc0\n\t"                               \
    "global_load_dwordx4 %9,  %17, off offset:64 sc0\n\t"                     \
    "global_load_dwordx4 %10, %17, off offset:128 sc0\n\t"                    \
    "global_load_dwordx4 %11, %17, off offset:192 sc0\n\t"                    \
    "global_load_dwordx4 %12, %17, off offset:256 sc0\n\t"                    \
    "global_load_dwordx4 %13, %17, off offset:320 sc0\n\t"                    \
    "global_load_dwordx4 %14, %17, off offset:384 sc0\n\t"                    \
    "global_load_dwordx4 %15, %17, off offset:448 sc0\n\t"                    \
    "s_waitcnt vmcnt(0)"                                                      \
    : "=&v"(A0),"=&v"(A1),"=&v"(A2),"=&v"(A3),"=&v"(A4),"=&v"(A5),"=&v"(A6), \
      "=&v"(A7),"=&v"(A8),"=&v"(A9),"=&v"(A10),"=&v"(A11),"=&v"(A12),         \
      "=&v"(A13),"=&v"(A14),"=&v"(A15)                                        \
    : "v"(HB0), "v"(HB1)                                                      \
    : "memory");

#define AS_FROM_A()                                                           \
  short8 AS[16] = {                                                           \
    __builtin_bit_cast(short8,A0), __builtin_bit_cast(short8,A1),             \
    __builtin_bit_cast(short8,A2), __builtin_bit_cast(short8,A3),             \
    __builtin_bit_cast(short8,A4), __builtin_bit_cast(short8,A5),             \
    __builtin_bit_cast(short8,A6), __builtin_bit_cast(short8,A7),             \
    __builtin_bit_cast(short8,A8), __builtin_bit_cast(short8,A9),             \
    __builtin_bit_cast(short8,A10),__builtin_bit_cast(short8,A11),            \
    __builtin_bit_cast(short8,A12),__builtin_bit_cast(short8,A13),            \
    __builtin_bit_cast(short8,A14),__builtin_bit_cast(short8,A15) };

  // ================= recurrence blocks (XCD0 = l0, XCD1 = l1) =================
  if (kind <= 1u) {
    const int l = (int)kind;
    unsigned* intraF = ctrl + (l == 0 ? CW_IF0 : CW_IF1);
    u16* Hloc        = (l == 0) ? H0L : H1L;
    const unsigned char* XGpk = (l == 0) ? XG0pk : XG1pk;
    float cA = 0.f, cB = 0.f;

    for (int s = 0; s < T_STEPS; ++s) {
      // (A) xg flag (L3, workers run far ahead -> usually 1 iteration)
      {
        const unsigned* xp = (l == 0) ? (ctrl + CW_XF0 + s * 32 + r)
                                      : (ctrl + CW_XF1 + (s & 15) * 32 + r);
        const unsigned need = (unsigned)(s + 1);
        while (__hip_atomic_load(xp, __ATOMIC_RELAXED, __HIP_MEMORY_SCOPE_AGENT) < need)
          __builtin_amdgcn_s_sleep(2);
      }
      // (B) intra h flags via L2/sc0 (the serial detect — ~200cy per iter)
      {
        const unsigned* p = intraF + (size_t)(lane & 31) * 16;
        for (;;) {
          unsigned v = ld_flag_sc0(p);
          if (__all((int)(v >= (unsigned)s))) break;
          __builtin_amdgcn_s_sleep(1);
        }
      }
      // (C) issue packed xg loads (L3) then h loads (L2) -> one overlapped wait
      const int slot = (l == 0) ? (s & 127) : (s & 15);
      const u64* xgq = (const u64*)(XGpk + ((size_t)(slot * 32 + r) * 512 + tid) * 16);
      u64 xd0 = __hip_atomic_load(xgq,     __ATOMIC_RELAXED, __HIP_MEMORY_SCOPE_AGENT);
      u64 xd1 = __hip_atomic_load(xgq + 1, __ATOMIC_RELAXED, __HIP_MEMORY_SCOPE_AGENT);
      const u16* hb0 = Hloc + (size_t)(s & 7) * BH + (size_t)l15 * 1024 + ks * 256 + lq * 8;
      const u16* hb1 = hb0 + 16 * 1024;
      f32x4 A0,A1,A2,A3,A4,A5,A6,A7,A8,A9,A10,A11,A12,A13,A14,A15;
      LOAD16_SC0(hb0, hb1);
      __builtin_amdgcn_sched_barrier(0);
      AS_FROM_A();

      f32x4 acc0[4] = {{0,0,0,0},{0,0,0,0},{0,0,0,0},{0,0,0,0}};
      f32x4 acc1[4] = {{0,0,0,0},{0,0,0,0},{0,0,0,0},{0,0,0,0}};
      MFMA_ALL(AS);
      RED_WRITE();

      float gsum[2][4];
      RED_READ(gsum);
      // unpack xg: word g = bf(mt0) | bf(mt1)<<16
      unsigned xwv[4] = { (unsigned)xd0, (unsigned)(xd0 >> 32),
                          (unsigned)xd1, (unsigned)(xd1 >> 32) };
      #pragma unroll
      for (int mt2 = 0; mt2 < 2; ++mt2) {
        const int m = m2 + mt2 * 16;
        float xg0f = __builtin_bit_cast(float, mt2 ? (xwv[0] & 0xFFFF0000u) : (xwv[0] << 16));
        float xg1f = __builtin_bit_cast(float, mt2 ? (xwv[1] & 0xFFFF0000u) : (xwv[1] << 16));
        float xg2f = __builtin_bit_cast(float, mt2 ? (xwv[2] & 0xFFFF0000u) : (xwv[2] << 16));
        float xg3f = __builtin_bit_cast(float, mt2 ? (xwv[3] & 0xFFFF0000u) : (xwv[3] << 16));
        const float G0 = gsum[mt2][0] + xg0f;
        const float G1 = gsum[mt2][1] + xg1f;
        const float G2 = gsum[mt2][2] + xg2f;
        const float G3 = gsum[mt2][3] + xg3f;
        const float cold = (s == 0) ? c0in[(size_t)l * 32768 + (size_t)m * 1024 + col]
                                    : (mt2 ? cB : cA);
        const float cn = sigm(G1) * cold + sigm(G0) * tanhf(G2);
        const float hn = sigm(G3) * tanhf(cn);
        if (mt2) cB = cn; else cA = cn;
        const unsigned hbv = f2bf(hn);
        st_u16_sc0(Hloc + (size_t)((s + 1) & 7) * BH + (size_t)m * 1024 + col, hbv);
        if (l == 0)
          __hip_atomic_store(H0X + (size_t)(s + 1) * BH + (size_t)m * 1024 + col,
                             (u16)hbv, __ATOMIC_RELAXED, __HIP_MEMORY_SCOPE_AGENT);
        else
          out[(size_t)s * BH + (size_t)m * 1024 + col] = hn;
        if (s == T_STEPS - 1) {
          out[MEM_ELEMS + (size_t)l * 32768 + (size_t)m * 1024 + col] = hn;
          out[MEM_ELEMS + 65536 + (size_t)l * 32768 + (size_t)m * 1024 + col] = cn;
        }
      }
      __syncthreads();   // drains all waves' stores; guards redf reuse
      if (tid == 0) {
        st_flag_sc0(intraF + (size_t)r * 16, (unsigned)(s + 1));
        if (l == 0) {
          __hip_atomic_store(&ctrl[CW_H0XF + r * 16], (unsigned)(s + 1),
                             __ATOMIC_RELAXED, __HIP_MEMORY_SCOPE_AGENT);
          if (r == 0)
            __hip_atomic_store(&ctrl[CW_L0P], (unsigned)(s + 1),
                               __ATOMIC_RELAXED, __HIP_MEMORY_SCOPE_AGENT);
        } else if (r == 0) {
          __hip_atomic_store(&ctrl[CW_L1P], (unsigned)(s + 1),
                             __ATOMIC_RELAXED, __HIP_MEMORY_SCOPE_AGENT);
        }
      }
    }
    return;
  }

  // ================= XG0 workers (X @ W_ih0^T + bias0), XCDs 2-4 =================
  if (kind == 2u) {
    unsigned* cnt = ctrl + CW_CNT0 + r;
    for (;;) {
      if (tid == 0) {
        unsigned t = __hip_atomic_fetch_add(cnt, 1u, __ATOMIC_RELAXED, __HIP_MEMORY_SCOPE_AGENT);
        redf[0][0][0][0] = __builtin_bit_cast(float, t);
      }
      __syncthreads();
      const unsigned s = __builtin_bit_cast(unsigned, redf[0][0][0][0]);
      __syncthreads();
      if (s >= (unsigned)T_STEPS) break;
      if (s >= 124u) {        // ring-128 reuse throttle (rare, quiet)
        if (wid == 0)
          while (__hip_atomic_load(&ctrl[CW_L0P], __ATOMIC_RELAXED, __HIP_MEMORY_SCOPE_AGENT)
                 < s - 120u) __builtin_amdgcn_s_sleep(32);
        __syncthreads();
      }

      const float* xs = X + (size_t)s * BH;
      short8 AS[16];
      #pragma unroll
      for (int kc = 0; kc < 8; ++kc) {
        const float* p0 = xs + (size_t)l15 * 1024 + ks * 256 + kc * 32 + lq * 8;
        const float* p1 = p0 + 16 * 1024;
        float4 a = *(const float4*)p0, b = *(const float4*)(p0 + 4);
        float4 c = *(const float4*)p1, d = *(const float4*)(p1 + 4);
        short8 s0, s1;
        s0[0]=(short)f2bf(a.x); s0[1]=(short)f2bf(a.y); s0[2]=(short)f2bf(a.z); s0[3]=(short)f2bf(a.w);
        s0[4]=(short)f2bf(b.x); s0[5]=(short)f2bf(b.y); s0[6]=(short)f2bf(b.z); s0[7]=(short)f2bf(b.w);
        s1[0]=(short)f2bf(c.x); s1[1]=(short)f2bf(c.y); s1[2]=(short)f2bf(c.z); s1[3]=(short)f2bf(c.w);
        s1[4]=(short)f2bf(d.x); s1[5]=(short)f2bf(d.y); s1[6]=(short)f2bf(d.z); s1[7]=(short)f2bf(d.w);
        AS[kc] = s0; AS[8 + kc] = s1;
      }
      f32x4 acc0[4] = {{0,0,0,0},{0,0,0,0},{0,0,0,0},{0,0,0,0}};
      f32x4 acc1[4] = {{0,0,0,0},{0,0,0,0},{0,0,0,0},{0,0,0,0}};
      MFMA_ALL(AS);
      RED_WRITE();
      float gsum[2][4];
      RED_READ(gsum);
      unsigned w[4];
      #pragma unroll
      for (int g = 0; g < 4; ++g)
        w[g] = (unsigned)f2bf(gsum[0][g] + bs[g]) | ((unsigned)f2bf(gsum[1][g] + bs[g]) << 16);
      u64* dq = (u64*)(XG0pk + ((size_t)((s & 127u) * 32 + r) * 512 + tid) * 16);
      __hip_atomic_store(dq,     (u64)w[0] | ((u64)w[1] << 32),
                         __ATOMIC_RELAXED, __HIP_MEMORY_SCOPE_AGENT);
      __hip_atomic_store(dq + 1, (u64)w[2] | ((u64)w[3] << 32),
                         __ATOMIC_RELAXED, __HIP_MEMORY_SCOPE_AGENT);
      __syncthreads();
      if (tid == 0)
        __hip_atomic_store(&ctrl[CW_XF0 + s * 32 + r], s + 1u,
                           __ATOMIC_RELAXED, __HIP_MEMORY_SCOPE_AGENT);
    }
    return;
  }

  // ================= XG1 workers (h0_out @ W_ih1^T + bias1), XCDs 5-7 =================
  {
    unsigned* cnt = ctrl + CW_CNT1 + r;
    for (;;) {
      if (tid == 0) {
        unsigned t = __hip_atomic_fetch_add(cnt, 1u, __ATOMIC_RELAXED, __HIP_MEMORY_SCOPE_AGENT);
        redf[0][0][0][0] = __builtin_bit_cast(float, t);
      }
      __syncthreads();
      const unsigned s = __builtin_bit_cast(unsigned, redf[0][0][0][0]);
      __syncthreads();
      if (s >= (unsigned)T_STEPS) break;
      // gate + ring throttle: WAVE 0 ONLY polls (storm fix), then block-broadcast
      if (wid == 0) {
        const unsigned* p = ctrl + CW_H0XF + (size_t)(lane & 31) * 16;
        for (;;) {
          unsigned v = __hip_atomic_load(p, __ATOMIC_RELAXED, __HIP_MEMORY_SCOPE_AGENT);
          if (__all((int)(v >= s + 1u))) break;
          __builtin_amdgcn_s_sleep(16);
        }
        if (s >= 13u)
          while (__hip_atomic_load(&ctrl[CW_L1P], __ATOMIC_RELAXED, __HIP_MEMORY_SCOPE_AGENT)
                 < s - 12u) __builtin_amdgcn_s_sleep(32);
      }
      __syncthreads();

      const u16* hb0 = H0X + (size_t)(s + 1) * BH + (size_t)l15 * 1024 + ks * 256 + lq * 8;
      const u16* hb1 = hb0 + 16 * 1024;
      short8 AS[16];
      #pragma unroll
      for (int kc = 0; kc < 8; ++kc) {
        AS[kc]     = ld_sc16(hb0 + kc * 32);
        AS[8 + kc] = ld_sc16(hb1 + kc * 32);
      }
      f32x4 acc0[4] = {{0,0,0,0},{0,0,0,0},{0,0,0,0},{0,0,0,0}};
      f32x4 acc1[4] = {{0,0,0,0},{0,0,0,0},{0,0,0,0},{0,0,0,0}};
      MFMA_ALL(AS);
      RED_WRITE();
      float gsum[2][4];
      RED_READ(gsum);
      unsigned w[4];
      #pragma unroll
      for (int g = 0; g < 4; ++g)
        w[g] = (unsigned)f2bf(gsum[0][g] + bs[g]) | ((unsigned)f2bf(gsum[1][g] + bs[g]) << 16);
      u64* dq = (u64*)(XG1pk + ((size_t)((s & 15u) * 32 + r) * 512 + tid) * 16);
      __hip_atomic_store(dq,     (u64)w[0] | ((u64)w[1] << 32),
                         __ATOMIC_RELAXED, __HIP_MEMORY_SCOPE_AGENT);
      __hip_atomic_store(dq + 1, (u64)w[2] | ((u64)w[3] << 32),
                         __ATOMIC_RELAXED, __HIP_MEMORY_SCOPE_AGENT);
      __syncthreads();
      if (tid == 0)
        __hip_atomic_store(&ctrl[CW_XF1 + (s & 15u) * 32 + r], s + 1u,
                           __ATOMIC_RELAXED, __HIP_MEMORY_SCOPE_AGENT);
    }
  }
#undef MFMA_ALL
#undef RED_WRITE
#undef RED_READ
#undef LOAD16_SC0
#undef AS_FROM_A
}

// ---------------- tier-2: per-step launches (round-1 proven) ----------------
__global__ void cvt_t2(const float* __restrict__ Wih, const float* __restrict__ Whh,
                       const float* __restrict__ bih, const float* __restrict__ bhh,
                       const float* __restrict__ h0,
                       u16* __restrict__ Wcat, float* __restrict__ bias,
                       u16* __restrict__ h0pp, u16* __restrict__ h1pp) {
  size_t idx = (size_t)blockIdx.x * blockDim.x + threadIdx.x;
  size_t stride = (size_t)gridDim.x * blockDim.x;
  const size_t NW = (size_t)2 * G4H * 2048;
  for (size_t i = idx; i < NW; i += stride) {
    size_t ln = i >> 11;
    int k = (int)(i & 2047);
    float v = (k < HID) ? Wih[ln * HID + k] : Whh[ln * HID + (k - HID)];
    Wcat[i] = f2bf(v);
  }
  for (size_t i = idx; i < (size_t)2 * G4H; i += stride) bias[i] = bih[i] + bhh[i];
  for (size_t i = idx; i < (size_t)2 * BH; i += stride) {
    unsigned short v = f2bf(h0[i]);
    if (i < (size_t)BH) h0pp[(size_t)BH + i] = v;
    else                h1pp[(size_t)BH + (i - BH)] = v;
  }
}

__global__ __launch_bounds__(256) void lstm_step(
    const float* __restrict__ input, const u16* __restrict__ Wcat,
    const float* __restrict__ bias, u16* __restrict__ h0pp, u16* __restrict__ h1pp,
    const float* __restrict__ c0, float* __restrict__ out, int t)
{
  const bool is_l1 = (blockIdx.x >= 128);
  const int s = is_l1 ? (t - 1) : t;
  if (s < 0 || s >= T_STEPS) return;
  const int l = is_l1 ? 1 : 0;
  const int cb = blockIdx.x & 127;
  const int j0 = cb << 3;
  const int tid = threadIdx.x;
  const int lane = tid & 63;
  const int wid = tid >> 6;
  const int l15 = lane & 15;
  const int lq  = lane >> 4;
  const int koff = lq << 3;
  const int k0 = wid << 9;

  const int row0 = (l15 < 8) ? (j0 + l15) : (HID + j0 + l15 - 8);
  const int row1 = (l15 < 8) ? (2 * HID + j0 + l15) : (3 * HID + j0 + l15 - 8);
  const u16* bp0 = Wcat + ((size_t)l * G4H + row0) * 2048 + k0 + koff;
  const u16* bp1 = Wcat + ((size_t)l * G4H + row1) * 2048 + k0 + koff;

  f32x4 acc00 = {0.f, 0.f, 0.f, 0.f};
  f32x4 acc01 = acc00, acc10 = acc00, acc11 = acc00;

  const bool a_f32 = (!is_l1) && (wid < 2);
  if (a_f32) {
    const float* base = input + (size_t)s * BH + k0 + koff;
    const float* af0 = base + (size_t)l15 * HID;
    const float* af1 = base + (size_t)(16 + l15) * HID;
    #pragma unroll 4
    for (int kss = 0; kss < 16; ++kss) {
      const int kk = kss * 32;
      short8 b0 = *(const short8*)(bp0 + kk);
      short8 b1 = *(const short8*)(bp1 + kk);
      float4 q0 = *(const float4*)(af0 + kk);
      float4 q1 = *(const float4*)(af0 + kk + 4);
      float4 y0 = *(const float4*)(af1 + kk);
      float4 y1 = *(const float4*)(af1 + kk + 4);
      short8 a0, a1;
      a0[0]=(short)f2bf(q0.x); a0[1]=(short)f2bf(q0.y); a0[2]=(short)f2bf(q0.z); a0[3]=(short)f2bf(q0.w);
      a0[4]=(short)f2bf(q1.x); a0[5]=(short)f2bf(q1.y); a0[6]=(short)f2bf(q1.z); a0[7]=(short)f2bf(q1.w);
      a1[0]=(short)f2bf(y0.x); a1[1]=(short)f2bf(y0.y); a1[2]=(short)f2bf(y0.z); a1[3]=(short)f2bf(y0.w);
      a1[4]=(short)f2bf(y1.x); a1[5]=(short)f2bf(y1.y); a1[6]=(short)f2bf(y1.z); a1[7]=(short)f2bf(y1.w);
      acc00 = __builtin_amdgcn_mfma_f32_16x16x32_bf16(a0, b0, acc00, 0, 0, 0);
      acc01 = __builtin_amdgcn_mfma_f32_16x16x32_bf16(a0, b1, acc01, 0, 0, 0);
      acc10 = __builtin_amdgcn_mfma_f32_16x16x32_bf16(a1, b0, acc10, 0, 0, 0);
      acc11 = __builtin_amdgcn_mfma_f32_16x16x32_bf16(a1, b1, acc11, 0, 0, 0);
    }
  } else {
    const u16* src; int ksrc;
    if (!is_l1)       { src = h0pp + (size_t)(((s + 1) & 1)) * BH; ksrc = k0 - HID; }
    else if (wid < 2) { src = h0pp + (size_t)((s & 1)) * BH;       ksrc = k0;       }
    else              { src = h1pp + (size_t)(((s + 1) & 1)) * BH; ksrc = k0 - HID; }
    const u16* ab0 = src + (size_t)l15 * HID + ksrc + koff;
    const u16* ab1 = src + (size_t)(16 + l15) * HID + ksrc + koff;
    #pragma unroll 4
    for (int kss = 0; kss < 16; ++kss) {
      const int kk = kss * 32;
      short8 b0 = *(const short8*)(bp0 + kk);
      short8 b1 = *(const short8*)(bp1 + kk);
      short8 a0 = *(const short8*)(ab0 + kk);
      short8 a1 = *(const short8*)(ab1 + kk);
      acc00 = __builtin_amdgcn_mfma_f32_16x16x32_bf16(a0, b0, acc00, 0, 0, 0);
      acc01 = __builtin_amdgcn_mfma_f32_16x16x32_bf16(a0, b1, acc01, 0, 0, 0);
      acc10 = __builtin_amdgcn_mfma_f32_16x16x32_bf16(a1, b0, acc10, 0, 0, 0);
      acc11 = __builtin_amdgcn_mfma_f32_16x16x32_bf16(a1, b1, acc11, 0, 0, 0);
    }
  }

  __shared__ float red[4][2][2][256];
  #pragma unroll
  for (int q = 0; q < 4; ++q) {
    red[wid][0][0][lane * 4 + q] = acc00[q];
    red[wid][0][1][lane * 4 + q] = acc01[q];
    red[wid][1][0][lane * 4 + q] = acc10[q];
    red[wid][1][1][lane * 4 + q] = acc11[q];
  }
  __syncthreads();

  const int m  = tid >> 3;
  const int jj = tid & 7;
  const int j  = j0 + jj;
  const int mt = m >> 4;
  const int mm = m & 15;
  const int rr = mm & 3;
  const int lbase = (mm >> 2) << 4;

  float g4[4];
  #pragma unroll
  for (int gate = 0; gate < 4; ++gate) {
    const int nt = gate >> 1;
    const int nn = ((gate & 1) << 3) + jj;
    const int li = (lbase | nn) * 4 + rr;
    float v = red[0][mt][nt][li] + red[1][mt][nt][li] +
              red[2][mt][nt][li] + red[3][mt][nt][li];
    g4[gate] = v + bias[l * G4H + gate * HID + j];
  }

  float* hT     = out + MEM_ELEMS;
  float* cstate = out + MEM_ELEMS + 2 * (size_t)BH;
  const size_t cidx = (size_t)l * BH + (size_t)m * HID + j;
  const float c_old = (s == 0) ? c0[cidx] : cstate[cidx];
  const float c_new = sigm(g4[1]) * c_old + sigm(g4[0]) * tanhf(g4[2]);
  const float h_new = sigm(g4[3]) * tanhf(c_new);
  cstate[cidx] = c_new;
  u16* ppw = (is_l1 ? h1pp : h0pp) + (size_t)(s & 1) * BH;
  ppw[m * HID + j] = f2bf(h_new);
  if (is_l1) out[(size_t)s * BH + (size_t)m * HID + j] = h_new;
  if (s == T_STEPS - 1) hT[cidx] = h_new;
}

// ---------------- tier-3: fp32 fallback ----------------
__global__ void fb_init(const float* __restrict__ h0, float* __restrict__ h0ppf,
                        float* __restrict__ h1ppf) {
  int i = blockIdx.x * blockDim.x + threadIdx.x;
  if (i < BH) h0ppf[BH + i] = h0[i];
  else if (i < 2 * BH) h1ppf[BH + (i - BH)] = h0[i];
}

__global__ __launch_bounds__(256) void fb_step(
    const float* __restrict__ input, const float* __restrict__ Wih,
    const float* __restrict__ Whh, const float* __restrict__ bih,
    const float* __restrict__ bhh, float* __restrict__ h0ppf, float* __restrict__ h1ppf,
    const float* __restrict__ c0, float* __restrict__ out, int t)
{
  const bool is_l1 = (blockIdx.x >= 128);
  const int s = is_l1 ? (t - 1) : t;
  if (s < 0 || s >= T_STEPS) return;
  const int l = is_l1 ? 1 : 0;
  const int cb = blockIdx.x & 127, j0 = cb << 3, tid = threadIdx.x;
  const float* xsrc = is_l1 ? (h0ppf + (size_t)(s & 1) * BH) : (input + (size_t)s * BH);
  const float* hsrc = (is_l1 ? h1ppf : h0ppf) + (size_t)((s + 1) & 1) * BH;
  const int c = tid & 31, mg = tid >> 5;
  const int gate = c >> 3, jc = c & 7;
  const int row = gate * HID + j0 + jc;
  const float* wi = Wih + ((size_t)l * G4H + row) * HID;
  const float* wh = Whh + ((size_t)l * G4H + row) * HID;
  float a0 = 0, a1 = 0, a2 = 0, a3 = 0;
  const float* x0 = xsrc + (size_t)(mg * 4 + 0) * HID;
  const float* x1 = xsrc + (size_t)(mg * 4 + 1) * HID;
  const float* x2 = xsrc + (size_t)(mg * 4 + 2) * HID;
  const float* x3 = xsrc + (size_t)(mg * 4 + 3) * HID;
  const float* h0p = hsrc + (size_t)(mg * 4 + 0) * HID;
  const float* h1p = hsrc + (size_t)(mg * 4 + 1) * HID;
  const float* h2p = hsrc + (size_t)(mg * 4 + 2) * HID;
  const float* h3p = hsrc + (size_t)(mg * 4 + 3) * HID;
  for (int k = 0; k < HID; ++k) {
    float wa = wi[k], wb2 = wh[k];
    a0 += x0[k] * wa + h0p[k] * wb2;
    a1 += x1[k] * wa + h1p[k] * wb2;
    a2 += x2[k] * wa + h2p[k] * wb2;
    a3 += x3[k] * wa + h3p[k] * wb2;
  }
  __shared__ float gl[32][32];
  const float bsum = bih[l * G4H + row] + bhh[l * G4H + row];
  gl[mg * 4 + 0][c] = a0 + bsum;
  gl[mg * 4 + 1][c] = a1 + bsum;
  gl[mg * 4 + 2][c] = a2 + bsum;
  gl[mg * 4 + 3][c] = a3 + bsum;
  __syncthreads();
  const int m = tid >> 3, jj = tid & 7, j = j0 + jj;
  float g4[4];
  #pragma unroll
  for (int g = 0; g < 4; ++g) g4[g] = gl[m][g * 8 + jj];
  float* hT = out + MEM_ELEMS;
  float* cstate = out + MEM_ELEMS + 2 * (size_t)BH;
  const size_t cidx = (size_t)l * BH + (size_t)m * HID + j;
  const float c_old = (s == 0) ? c0[cidx] : cstate[cidx];
  const float c_new = sigm(g4[1]) * c_old + sigm(g4[0]) * tanhf(g4[2]);
  const float h_new = sigm(g4[3]) * tanhf(c_new);
  cstate[cidx] = c_new;
  float* ppw = (is_l1 ? h1ppf : h0ppf) + (size_t)(s & 1) * BH;
  ppw[m * HID + j] = h_new;
  if (is_l1) out[(size_t)s * BH + (size_t)m * HID + j] = h_new;
  if (s == T_STEPS - 1) hT[cidx] = h_new;
}

extern "C" void kernel_launch(void* const* d_in, const int* in_sizes, int n_in,
                              void* d_out, int out_size, void* d_ws, size_t ws_size,
                              hipStream_t stream) {
  const float* input = (const float*)d_in[0];
  const float* h0    = (const float*)d_in[1];
  const float* c0    = (const float*)d_in[2];
  const float* Wih   = (const float*)d_in[3];
  const float* Whh   = (const float*)d_in[4];
  const float* bih   = (const float*)d_in[5];
  const float* bhh   = (const float*)d_in[6];
  float* out = (float*)d_out;
  char* ws = (char*)d_ws;

  if (ws_size >= WS_MESH) {
    int occ = 0;   // must be exactly 1 block/CU for the XCD role claim
    (void)hipOccupancyMaxActiveBlocksPerMultiprocessor(&occ, lstm_mesh, 512, 0);
    if (occ == 1) {
      u16*   WFHH = (u16*)(ws + OFF_WFHH);
      u16*   WFI0 = (u16*)(ws + OFF_WFI0);
      u16*   WFI1 = (u16*)(ws + OFF_WFI1);
      float* bias = (float*)(ws + OFF_BIAS);
      u16*   H0L  = (u16*)(ws + OFF_H0L);
      u16*   H1L  = (u16*)(ws + OFF_H1L);
      u16*   H0X  = (u16*)(ws + OFF_H0X);
      unsigned char* XG0pk = (unsigned char*)(ws + OFF_XG0);
      unsigned char* XG1pk = (unsigned char*)(ws + OFF_XG1);
      unsigned* ctrl = (unsigned*)(ws + OFF_CTRL);
      hipMemsetAsync(ws + OFF_CTRL, 0, SZ_CTRL, stream);
      cvt_mesh<<<2048, 256, 0, stream>>>(Wih, Whh, bih, bhh, h0,
                                         WFHH, WFI0, WFI1, bias, H0L, H1L);
      lstm_mesh<<<256, 512, 0, stream>>>(input, c0, out, WFHH, WFI0, WFI1, bias,
                                         H0L, H1L, H0X, XG0pk, XG1pk, ctrl);
      return;
    }
  }
  if (ws_size >= WS_STEP) {
    u16*   Wcat = (u16*)(ws + T2_W);
    float* bias = (float*)(ws + T2_BIAS);
    u16*   h0pp = (u16*)(ws + T2_H0);
    u16*   h1pp = (u16*)(ws + T2_H1);
    cvt_t2<<<4096, 256, 0, stream>>>(Wih, Whh, bih, bhh, h0, Wcat, bias, h0pp, h1pp);
    for (int t = 0; t <= T_STEPS; ++t)
      lstm_step<<<256, 256, 0, stream>>>(input, Wcat, bias, h0pp, h1pp, c0, out, t);
  } else {
    float* h0ppf = (float*)ws;
    float* h1ppf = (float*)(ws + (size_t)2 * BH * 4);
    fb_init<<<256, 256, 0, stream>>>(h0, h0ppf, h1ppf);
    for (int t = 0; t <= T_STEPS; ++t)
      fb_step<<<256, 256, 0, stream>>>(input, Wih, Whh, bih, bhh, h0ppf, h1ppf, c0, out, t);
  }
}

// Round 8
// 4739.148 us; speedup vs baseline: 1.3374x; 1.3374x over previous
//
#include <hip/hip_runtime.h>
#include <hip/hip_bf16.h>

// LSTM T=512 B=32 IN=H=1024 L=2. fp32 in/out, bf16 MFMA internally.
// Round 8: round-4 structure (free-running blocks, versioned h + per-producer
// flag words) with the coherent h loads BATCHED (issue all, wait once) to kill
// the per-iteration L3-latency serialization that set r4's 10.3us/step.

namespace {
constexpr int T_STEPS = 512;
constexpr int BATCH   = 32;
constexpr int HID     = 1024;
constexpr int G4H     = 4096;
constexpr int KCAT    = 2048;
constexpr int BH      = BATCH * HID;                 // 32768
constexpr size_t MEM_ELEMS = (size_t)T_STEPS * BH;   // 16,777,216

// workspace layout (bytes) — identical to round 4
constexpr size_t OFF_W    = 0;
constexpr size_t SZ_W     = (size_t)2 * G4H * KCAT * 2;     // 33.55 MB bf16 W_cat
constexpr size_t OFF_BIAS = OFF_W + SZ_W;                   // f32 [2][4096]
constexpr size_t OFF_H0V  = OFF_BIAS + 32768;               // bf16 [513][32][1024]
constexpr size_t SZ_HV    = (size_t)(T_STEPS + 1) * BH * 2; // 33.62 MB
constexpr size_t OFF_H1V  = OFF_H0V + SZ_HV;
constexpr size_t OFF_FLAG = OFF_H1V + SZ_HV;                // u32[2][128] @16B stride
constexpr size_t SZ_FLAG  = 4096;
constexpr size_t OFF_X    = OFF_FLAG + SZ_FLAG;             // bf16 X [512][32][1024]
constexpr size_t WS_ASYNC = OFF_X + MEM_ELEMS * 2;          // ~135 MB
constexpr size_t WS_STEP  = OFF_H0V + (size_t)4 * BH * 2;   // tier-2: pp buffers only
}

typedef __attribute__((ext_vector_type(8))) short short8;
typedef __attribute__((ext_vector_type(4))) float f32x4;
typedef unsigned short u16;
typedef unsigned long long u64;

__device__ inline unsigned short f2bf(float x) {
  unsigned u = __builtin_bit_cast(unsigned, x);
  u += 0x7fffu + ((u >> 16) & 1u);          // RNE
  return (unsigned short)(u >> 16);
}
__device__ inline float sigm(float x) { return 1.0f / (1.0f + __expf(-x)); }

// ---------------- conversion: W_cat bf16, bias sum, initial h, X bf16 ----------------
__global__ void cvt_kernel(const float* __restrict__ Wih, const float* __restrict__ Whh,
                           const float* __restrict__ bih, const float* __restrict__ bhh,
                           const float* __restrict__ h0, const float* __restrict__ input,
                           u16* __restrict__ Wcat, float* __restrict__ bias,
                           u16* __restrict__ H0i, u16* __restrict__ H1i,
                           u16* __restrict__ Xbf) {
  size_t idx = (size_t)blockIdx.x * blockDim.x + threadIdx.x;
  size_t stride = (size_t)gridDim.x * blockDim.x;
  const size_t NW = (size_t)2 * G4H * KCAT;
  for (size_t i = idx; i < NW; i += stride) {
    size_t ln = i >> 11;                 // l*4096 + n
    int k = (int)(i & 2047);
    float v = (k < HID) ? Wih[ln * HID + k] : Whh[ln * HID + (k - HID)];
    Wcat[i] = f2bf(v);
  }
  for (size_t i = idx; i < (size_t)2 * G4H; i += stride) bias[i] = bih[i] + bhh[i];
  for (size_t i = idx; i < (size_t)2 * BH; i += stride) {
    unsigned short v = f2bf(h0[i]);
    if (i < (size_t)BH) H0i[i] = v;       // slot 0 = h at time 0
    else                H1i[i - BH] = v;
  }
  if (Xbf) {
    for (size_t i = idx; i < MEM_ELEMS; i += stride) Xbf[i] = f2bf(input[i]);
  }
}

// wait until all 128 producer slots (16B stride) of `fl` reach `needed`
__device__ inline void wait_flag_ge(const unsigned* fl, int lane, unsigned needed) {
  const unsigned* p0 = fl + lane * 4;
  const unsigned* p1 = fl + (lane + 64) * 4;
  while (true) {
    unsigned a = __hip_atomic_load(p0, __ATOMIC_RELAXED, __HIP_MEMORY_SCOPE_AGENT);
    unsigned b = __hip_atomic_load(p1, __ATOMIC_RELAXED, __HIP_MEMORY_SCOPE_AGENT);
    if (__all((int)(a >= needed && b >= needed))) break;
    __builtin_amdgcn_s_sleep(2);
  }
  asm volatile("" ::: "memory");   // keep h loads below the poll
}

// ---- batched-load MFMA halves: issue ALL A-frag loads, wait once, then MFMA ----
// (fix for r4's per-iteration load->MFMA serialization: 32 dependent ~800cy
//  L3 stalls ≈ 10.7us/step. Unrolled const-indexed arrays stay in VGPRs.)

__device__ __attribute__((always_inline)) void mfma_batched_sc(
    const unsigned char* smem, const u16* ab0, const u16* ab1,
    int kbyte_base, int xsw, int l15,
    f32x4& acc00, f32x4& acc01, f32x4& acc10, f32x4& acc11) {
  u64 ra0[16], ra1[16], rb0[16], rb1[16];
  #pragma unroll
  for (int ks = 0; ks < 16; ++ks) {
    const u64* q0 = (const u64*)(ab0 + ks * 32);
    const u64* q1 = (const u64*)(ab1 + ks * 32);
    ra0[ks] = __hip_atomic_load(q0,     __ATOMIC_RELAXED, __HIP_MEMORY_SCOPE_AGENT);
    ra1[ks] = __hip_atomic_load(q0 + 1, __ATOMIC_RELAXED, __HIP_MEMORY_SCOPE_AGENT);
    rb0[ks] = __hip_atomic_load(q1,     __ATOMIC_RELAXED, __HIP_MEMORY_SCOPE_AGENT);
    rb1[ks] = __hip_atomic_load(q1 + 1, __ATOMIC_RELAXED, __HIP_MEMORY_SCOPE_AGENT);
  }
  #pragma unroll
  for (int ks = 0; ks < 16; ++ks) {
    const int kb2 = kbyte_base + ks * 64;
    short8 b0 = *(const short8*)(smem + l15 * 4096 + (kb2 ^ xsw));
    short8 b1 = *(const short8*)(smem + (16 + l15) * 4096 + (kb2 ^ xsw));
    union { u64 u[2]; short8 s; } ua, ub;
    ua.u[0] = ra0[ks]; ua.u[1] = ra1[ks];
    ub.u[0] = rb0[ks]; ub.u[1] = rb1[ks];
    acc00 = __builtin_amdgcn_mfma_f32_16x16x32_bf16(ua.s, b0, acc00, 0, 0, 0);
    acc01 = __builtin_amdgcn_mfma_f32_16x16x32_bf16(ua.s, b1, acc01, 0, 0, 0);
    acc10 = __builtin_amdgcn_mfma_f32_16x16x32_bf16(ub.s, b0, acc10, 0, 0, 0);
    acc11 = __builtin_amdgcn_mfma_f32_16x16x32_bf16(ub.s, b1, acc11, 0, 0, 0);
  }
}

__device__ __attribute__((always_inline)) void mfma_batched_pl(
    const unsigned char* smem, const u16* ab0, const u16* ab1,
    int kbyte_base, int xsw, int l15,
    f32x4& acc00, f32x4& acc01, f32x4& acc10, f32x4& acc11) {
  u64 ra0[16], ra1[16], rb0[16], rb1[16];
  #pragma unroll
  for (int ks = 0; ks < 16; ++ks) {
    const u64* q0 = (const u64*)(ab0 + ks * 32);
    const u64* q1 = (const u64*)(ab1 + ks * 32);
    ra0[ks] = q0[0]; ra1[ks] = q0[1];
    rb0[ks] = q1[0]; rb1[ks] = q1[1];
  }
  #pragma unroll
  for (int ks = 0; ks < 16; ++ks) {
    const int kb2 = kbyte_base + ks * 64;
    short8 b0 = *(const short8*)(smem + l15 * 4096 + (kb2 ^ xsw));
    short8 b1 = *(const short8*)(smem + (16 + l15) * 4096 + (kb2 ^ xsw));
    union { u64 u[2]; short8 s; } ua, ub;
    ua.u[0] = ra0[ks]; ua.u[1] = ra1[ks];
    ub.u[0] = rb0[ks]; ub.u[1] = rb1[ks];
    acc00 = __builtin_amdgcn_mfma_f32_16x16x32_bf16(ua.s, b0, acc00, 0, 0, 0);
    acc01 = __builtin_amdgcn_mfma_f32_16x16x32_bf16(ua.s, b1, acc01, 0, 0, 0);
    acc10 = __builtin_amdgcn_mfma_f32_16x16x32_bf16(ub.s, b0, acc10, 0, 0, 0);
    acc11 = __builtin_amdgcn_mfma_f32_16x16x32_bf16(ub.s, b1, acc11, 0, 0, 0);
  }
}

// ---------------- persistent free-running kernel ----------------
__global__ __launch_bounds__(256, 1) void lstm_async(
    const u16* __restrict__ Xbf, const u16* __restrict__ Wcat,
    const float* __restrict__ bias, u16* __restrict__ H0v, u16* __restrict__ H1v,
    const float* __restrict__ c0, float* __restrict__ out, unsigned* __restrict__ flags)
{
  // 128 KiB swizzled weights + 16 KiB reduction + 512 B h-stage
  __shared__ __align__(16) unsigned char smem[131072 + 16384 + 512];
  float* redf   = (float*)(smem + 131072);
  u16*   hstage = (u16*)(smem + 131072 + 16384);

  const bool is_l1 = (blockIdx.x >= 128);
  const int l  = is_l1 ? 1 : 0;
  const int cb = blockIdx.x & 127;
  const int j0 = cb << 3;                  // 8 hidden units per block
  const int tid = threadIdx.x;
  const int lane = tid & 63;
  const int wid  = tid >> 6;
  const int l15  = lane & 15;
  const int lq   = lane >> 4;
  const int koff = lq << 3;
  const int k0   = wid << 9;               // wave K-slice: 512
  const int xsw  = (l15 & 7) << 4;         // LDS XOR swizzle for B reads
  const int kbyte_base = (k0 + koff) * 2;

  // ---- stage this block's 32 weight rows into LDS (XOR-swizzled) ----
  {
    const int kb = tid * 16;               // byte within a 4096B row
    for (int pr = 0; pr < 32; ++pr) {      // packed rows: [i x8][f x8][g x8][o x8]
      const u16* g = Wcat + ((size_t)l * G4H + (size_t)(pr >> 3) * HID + j0 + (pr & 7)) * KCAT;
      short8 v = *(const short8*)((const char*)g + kb);
      *(short8*)(smem + pr * 4096 + (kb ^ ((pr & 7) << 4))) = v;
    }
  }

  // elementwise mapping (one (m, jj) per thread)
  const int m  = tid >> 3;
  const int jj = tid & 7;
  const int j  = j0 + jj;
  const int mt = m >> 4;
  const int mm = m & 15;
  const int rr = mm & 3;
  const int lbase = (mm >> 2) << 4;
  float b4[4];
  #pragma unroll
  for (int g = 0; g < 4; ++g) b4[g] = bias[l * G4H + g * HID + j];

  float* hT = out + MEM_ELEMS;                      // [2][32][1024]
  float* cT = out + MEM_ELEMS + 2 * (size_t)BH;
  const size_t cidx = (size_t)l * BH + (size_t)m * HID + j;
  float c_reg = 0.f;
  u16* Hw = is_l1 ? H1v : H0v;
  unsigned* myflag = flags + (size_t)(l * 128 + cb) * 4;
  __syncthreads();

  for (int s = 0; s < T_STEPS; ++s) {
    // per-wave source & dependency (versioned flags: value s+1 == h@s+1 ready)
    const u16* src; int ksrc; const unsigned* fl; unsigned need; bool plain = false;
    if (!is_l1) {
      if (wid < 2) { src = Xbf + (size_t)s * BH; ksrc = k0; fl = flags; need = 0; plain = true; }
      else         { src = H0v + (size_t)s * BH; ksrc = k0 - HID; fl = flags; need = (unsigned)s; }
    } else {
      if (wid < 2) { src = H0v + (size_t)(s + 1) * BH; ksrc = k0; fl = flags; need = (unsigned)(s + 1); }
      else         { src = H1v + (size_t)s * BH; ksrc = k0 - HID; fl = flags + 512; need = (unsigned)s; }
    }
    if (need) wait_flag_ge(fl, lane, need);

    const u16* ab0 = src + (size_t)l15 * HID + ksrc + koff;
    const u16* ab1 = src + (size_t)(16 + l15) * HID + ksrc + koff;
    f32x4 acc00 = {0.f, 0.f, 0.f, 0.f};
    f32x4 acc01 = acc00, acc10 = acc00, acc11 = acc00;
    if (plain) mfma_batched_pl(smem, ab0, ab1, kbyte_base, xsw, l15, acc00, acc01, acc10, acc11);
    else       mfma_batched_sc(smem, ab0, ab1, kbyte_base, xsw, l15, acc00, acc01, acc10, acc11);

    *(f32x4*)(redf + ((wid * 2 + 0) * 2 + 0) * 256 + lane * 4) = acc00;
    *(f32x4*)(redf + ((wid * 2 + 0) * 2 + 1) * 256 + lane * 4) = acc01;
    *(f32x4*)(redf + ((wid * 2 + 1) * 2 + 0) * 256 + lane * 4) = acc10;
    *(f32x4*)(redf + ((wid * 2 + 1) * 2 + 1) * 256 + lane * 4) = acc11;
    __syncthreads();   // A: accs staged

    float g4[4];
    #pragma unroll
    for (int gate = 0; gate < 4; ++gate) {
      const int nt = gate >> 1;
      const int nn = ((gate & 1) << 3) + jj;
      const int li = (lbase | nn) * 4 + rr;
      float v = redf[((0 * 2 + mt) * 2 + nt) * 256 + li] +
                redf[((1 * 2 + mt) * 2 + nt) * 256 + li] +
                redf[((2 * 2 + mt) * 2 + nt) * 256 + li] +
                redf[((3 * 2 + mt) * 2 + nt) * 256 + li];
      g4[gate] = v + b4[gate];
    }
    const float c_old = (s == 0) ? c0[cidx] : c_reg;
    const float ig = sigm(g4[0]);
    const float fg = sigm(g4[1]);
    const float gg = tanhf(g4[2]);
    const float og = sigm(g4[3]);
    const float c_new = fg * c_old + ig * gg;
    const float h_new = og * tanhf(c_new);
    c_reg = c_new;
    hstage[tid] = f2bf(h_new);
    if (is_l1) out[(size_t)s * BH + (size_t)m * HID + j] = h_new;
    if (s == T_STEPS - 1) { hT[cidx] = h_new; cT[cidx] = c_new; }
    __syncthreads();   // B: hstage ready, redf consumed

    // wave 3 publishes h chunk (write-through stores) + fires versioned flag
    if (wid == 3) {
      const int w2 = lane * 2;            // word-pair index in [0,128)
      unsigned lo0 = (unsigned)hstage[2 * w2]     | ((unsigned)hstage[2 * w2 + 1] << 16);
      unsigned lo1 = (unsigned)hstage[2 * w2 + 2] | ((unsigned)hstage[2 * w2 + 3] << 16);
      u64 v = (u64)lo0 | ((u64)lo1 << 32);
      const int mrow = w2 >> 2;           // lane>>1
      const int jp   = w2 & 3;            // {0,2}
      unsigned* b32 = (unsigned*)(Hw + (size_t)(s + 1) * BH);
      __hip_atomic_store((u64*)(b32 + mrow * 512 + (j0 >> 1) + jp), v,
                         __ATOMIC_RELAXED, __HIP_MEMORY_SCOPE_AGENT);
      asm volatile("s_waitcnt vmcnt(0)" ::: "memory");
      if (lane == 0)
        __hip_atomic_store(myflag, (unsigned)(s + 1),
                           __ATOMIC_RELAXED, __HIP_MEMORY_SCOPE_AGENT);
    }
  }
}

// ---------------- tier-2: per-step launches (round-1, known-good) ----------------
__global__ __launch_bounds__(256) void lstm_step(
    const float* __restrict__ input, const u16* __restrict__ Wcat,
    const float* __restrict__ bias, u16* __restrict__ h0pp, u16* __restrict__ h1pp,
    const float* __restrict__ c0, float* __restrict__ out, int t)
{
  const bool is_l1 = (blockIdx.x >= 128);
  const int s = is_l1 ? (t - 1) : t;
  if (s < 0 || s >= T_STEPS) return;
  const int l = is_l1 ? 1 : 0;
  const int cb = blockIdx.x & 127;
  const int j0 = cb << 3;
  const int tid = threadIdx.x;
  const int lane = tid & 63;
  const int wid = tid >> 6;
  const int l15 = lane & 15;
  const int lq  = lane >> 4;
  const int koff = lq << 3;
  const int k0 = wid << 9;

  const int row0 = (l15 < 8) ? (j0 + l15) : (HID + j0 + l15 - 8);
  const int row1 = (l15 < 8) ? (2 * HID + j0 + l15) : (3 * HID + j0 + l15 - 8);
  const u16* bp0 = Wcat + ((size_t)l * G4H + row0) * KCAT + k0 + koff;
  const u16* bp1 = Wcat + ((size_t)l * G4H + row1) * KCAT + k0 + koff;

  f32x4 acc00 = {0.f, 0.f, 0.f, 0.f};
  f32x4 acc01 = acc00, acc10 = acc00, acc11 = acc00;

  const bool a_f32 = (!is_l1) && (wid < 2);
  if (a_f32) {
    const float* base = input + (size_t)s * BH + k0 + koff;
    const float* af0 = base + (size_t)l15 * HID;
    const float* af1 = base + (size_t)(16 + l15) * HID;
    #pragma unroll 4
    for (int ks = 0; ks < 16; ++ks) {
      const int kk = ks * 32;
      short8 b0 = *(const short8*)(bp0 + kk);
      short8 b1 = *(const short8*)(bp1 + kk);
      float4 x0 = *(const float4*)(af0 + kk);
      float4 x1 = *(const float4*)(af0 + kk + 4);
      float4 y0 = *(const float4*)(af1 + kk);
      float4 y1 = *(const float4*)(af1 + kk + 4);
      short8 a0, a1;
      a0[0] = (short)f2bf(x0.x); a0[1] = (short)f2bf(x0.y);
      a0[2] = (short)f2bf(x0.z); a0[3] = (short)f2bf(x0.w);
      a0[4] = (short)f2bf(x1.x); a0[5] = (short)f2bf(x1.y);
      a0[6] = (short)f2bf(x1.z); a0[7] = (short)f2bf(x1.w);
      a1[0] = (short)f2bf(y0.x); a1[1] = (short)f2bf(y0.y);
      a1[2] = (short)f2bf(y0.z); a1[3] = (short)f2bf(y0.w);
      a1[4] = (short)f2bf(y1.x); a1[5] = (short)f2bf(y1.y);
      a1[6] = (short)f2bf(y1.z); a1[7] = (short)f2bf(y1.w);
      acc00 = __builtin_amdgcn_mfma_f32_16x16x32_bf16(a0, b0, acc00, 0, 0, 0);
      acc01 = __builtin_amdgcn_mfma_f32_16x16x32_bf16(a0, b1, acc01, 0, 0, 0);
      acc10 = __builtin_amdgcn_mfma_f32_16x16x32_bf16(a1, b0, acc10, 0, 0, 0);
      acc11 = __builtin_amdgcn_mfma_f32_16x16x32_bf16(a1, b1, acc11, 0, 0, 0);
    }
  } else {
    const u16* src; int ksrc;
    if (!is_l1)       { src = h0pp + (size_t)(((s + 1) & 1)) * BH; ksrc = k0 - HID; }
    else if (wid < 2) { src = h0pp + (size_t)((s & 1)) * BH;       ksrc = k0;       }
    else              { src = h1pp + (size_t)(((s + 1) & 1)) * BH; ksrc = k0 - HID; }
    const u16* ab0 = src + (size_t)l15 * HID + ksrc + koff;
    const u16* ab1 = src + (size_t)(16 + l15) * HID + ksrc + koff;
    #pragma unroll 4
    for (int ks = 0; ks < 16; ++ks) {
      const int kk = ks * 32;
      short8 b0 = *(const short8*)(bp0 + kk);
      short8 b1 = *(const short8*)(bp1 + kk);
      short8 a0 = *(const short8*)(ab0 + kk);
      short8 a1 = *(const short8*)(ab1 + kk);
      acc00 = __builtin_amdgcn_mfma_f32_16x16x32_bf16(a0, b0, acc00, 0, 0, 0);
      acc01 = __builtin_amdgcn_mfma_f32_16x16x32_bf16(a0, b1, acc01, 0, 0, 0);
      acc10 = __builtin_amdgcn_mfma_f32_16x16x32_bf16(a1, b0, acc10, 0, 0, 0);
      acc11 = __builtin_amdgcn_mfma_f32_16x16x32_bf16(a1, b1, acc11, 0, 0, 0);
    }
  }

  __shared__ float red[4][2][2][256];
  #pragma unroll
  for (int r = 0; r < 4; ++r) {
    red[wid][0][0][lane * 4 + r] = acc00[r];
    red[wid][0][1][lane * 4 + r] = acc01[r];
    red[wid][1][0][lane * 4 + r] = acc10[r];
    red[wid][1][1][lane * 4 + r] = acc11[r];
  }
  __syncthreads();

  const int m  = tid >> 3;
  const int jj = tid & 7;
  const int j  = j0 + jj;
  const int mt = m >> 4;
  const int mm = m & 15;
  const int rr = mm & 3;
  const int lbase = (mm >> 2) << 4;

  float g4[4];
  #pragma unroll
  for (int gate = 0; gate < 4; ++gate) {
    const int nt = gate >> 1;
    const int nn = ((gate & 1) << 3) + jj;
    const int li = (lbase | nn) * 4 + rr;
    float v = red[0][mt][nt][li] + red[1][mt][nt][li] +
              red[2][mt][nt][li] + red[3][mt][nt][li];
    g4[gate] = v + bias[l * G4H + gate * HID + j];
  }

  float* hT     = out + MEM_ELEMS;
  float* cstate = out + MEM_ELEMS + 2 * (size_t)BH;
  const size_t cidx = (size_t)l * BH + (size_t)m * HID + j;
  const float c_old = (s == 0) ? c0[cidx] : cstate[cidx];
  const float ig = sigm(g4[0]);
  const float fg = sigm(g4[1]);
  const float gg = tanhf(g4[2]);
  const float og = sigm(g4[3]);
  const float c_new = fg * c_old + ig * gg;
  const float h_new = og * tanhf(c_new);
  cstate[cidx] = c_new;
  u16* ppw = (is_l1 ? h1pp : h0pp) + (size_t)(s & 1) * BH;
  ppw[m * HID + j] = f2bf(h_new);
  if (is_l1) out[(size_t)s * BH + (size_t)m * HID + j] = h_new;
  if (s == T_STEPS - 1) hT[cidx] = h_new;
}

// ---------------- tier-3: fp32 fallback ----------------
__global__ void fb_init(const float* __restrict__ h0, float* __restrict__ h0ppf,
                        float* __restrict__ h1ppf) {
  int i = blockIdx.x * blockDim.x + threadIdx.x;
  if (i < BH) h0ppf[BH + i] = h0[i];
  else if (i < 2 * BH) h1ppf[BH + (i - BH)] = h0[i];
}

__global__ __launch_bounds__(256) void fb_step(
    const float* __restrict__ input, const float* __restrict__ Wih,
    const float* __restrict__ Whh, const float* __restrict__ bih,
    const float* __restrict__ bhh, float* __restrict__ h0ppf, float* __restrict__ h1ppf,
    const float* __restrict__ c0, float* __restrict__ out, int t)
{
  const bool is_l1 = (blockIdx.x >= 128);
  const int s = is_l1 ? (t - 1) : t;
  if (s < 0 || s >= T_STEPS) return;
  const int l = is_l1 ? 1 : 0;
  const int cb = blockIdx.x & 127, j0 = cb << 3, tid = threadIdx.x;
  const float* xsrc = is_l1 ? (h0ppf + (size_t)(s & 1) * BH) : (input + (size_t)s * BH);
  const float* hsrc = (is_l1 ? h1ppf : h0ppf) + (size_t)((s + 1) & 1) * BH;
  const int c = tid & 31, mg = tid >> 5;
  const int gate = c >> 3, jc = c & 7;
  const int row = gate * HID + j0 + jc;
  const float* wi = Wih + ((size_t)l * G4H + row) * HID;
  const float* wh = Whh + ((size_t)l * G4H + row) * HID;
  float a0 = 0, a1 = 0, a2 = 0, a3 = 0;
  const float* x0 = xsrc + (size_t)(mg * 4 + 0) * HID;
  const float* x1 = xsrc + (size_t)(mg * 4 + 1) * HID;
  const float* x2 = xsrc + (size_t)(mg * 4 + 2) * HID;
  const float* x3 = xsrc + (size_t)(mg * 4 + 3) * HID;
  const float* h0p = hsrc + (size_t)(mg * 4 + 0) * HID;
  const float* h1p = hsrc + (size_t)(mg * 4 + 1) * HID;
  const float* h2p = hsrc + (size_t)(mg * 4 + 2) * HID;
  const float* h3p = hsrc + (size_t)(mg * 4 + 3) * HID;
  for (int k = 0; k < HID; ++k) {
    float wa = wi[k], wb = wh[k];
    a0 += x0[k] * wa + h0p[k] * wb;
    a1 += x1[k] * wa + h1p[k] * wb;
    a2 += x2[k] * wa + h2p[k] * wb;
    a3 += x3[k] * wa + h3p[k] * wb;
  }
  __shared__ float gl[32][32];
  const float bsum = bih[l * G4H + row] + bhh[l * G4H + row];
  gl[mg * 4 + 0][c] = a0 + bsum;
  gl[mg * 4 + 1][c] = a1 + bsum;
  gl[mg * 4 + 2][c] = a2 + bsum;
  gl[mg * 4 + 3][c] = a3 + bsum;
  __syncthreads();
  const int m = tid >> 3, jj = tid & 7, j = j0 + jj;
  float g4[4];
  #pragma unroll
  for (int g = 0; g < 4; ++g) g4[g] = gl[m][g * 8 + jj];
  float* hT = out + MEM_ELEMS;
  float* cstate = out + MEM_ELEMS + 2 * (size_t)BH;
  const size_t cidx = (size_t)l * BH + (size_t)m * HID + j;
  const float c_old = (s == 0) ? c0[cidx] : cstate[cidx];
  const float ig = sigm(g4[0]);
  const float fg = sigm(g4[1]);
  const float gg = tanhf(g4[2]);
  const float og = sigm(g4[3]);
  const float c_new = fg * c_old + ig * gg;
  const float h_new = og * tanhf(c_new);
  cstate[cidx] = c_new;
  float* ppw = (is_l1 ? h1ppf : h0ppf) + (size_t)(s & 1) * BH;
  ppw[m * HID + j] = h_new;
  if (is_l1) out[(size_t)s * BH + (size_t)m * HID + j] = h_new;
  if (s == T_STEPS - 1) hT[cidx] = h_new;
}

extern "C" void kernel_launch(void* const* d_in, const int* in_sizes, int n_in,
                              void* d_out, int out_size, void* d_ws, size_t ws_size,
                              hipStream_t stream) {
  const float* input = (const float*)d_in[0];
  const float* h0    = (const float*)d_in[1];
  const float* c0    = (const float*)d_in[2];
  const float* Wih   = (const float*)d_in[3];
  const float* Whh   = (const float*)d_in[4];
  const float* bih   = (const float*)d_in[5];
  const float* bhh   = (const float*)d_in[6];
  float* out = (float*)d_out;
  char* ws = (char*)d_ws;

  if (ws_size >= WS_ASYNC) {
    u16*   Wcat = (u16*)(ws + OFF_W);
    float* bias = (float*)(ws + OFF_BIAS);
    u16*   H0v  = (u16*)(ws + OFF_H0V);
    u16*   H1v  = (u16*)(ws + OFF_H1V);
    unsigned* flags = (unsigned*)(ws + OFF_FLAG);
    u16*   Xbf  = (u16*)(ws + OFF_X);

    int occ = 0;   // all 256 blocks must be co-resident for free-running flags
    (void)hipOccupancyMaxActiveBlocksPerMultiprocessor(&occ, lstm_async, 256, 0);
    if (occ >= 1) {
      cvt_kernel<<<4096, 256, 0, stream>>>(Wih, Whh, bih, bhh, h0, input,
                                           Wcat, bias, H0v, H1v, Xbf);
      hipMemsetAsync(ws + OFF_FLAG, 0, SZ_FLAG, stream);
      lstm_async<<<256, 256, 0, stream>>>(Xbf, Wcat, bias, H0v, H1v, c0, out, flags);
      return;
    }
  }
  if (ws_size >= WS_STEP) {
    u16*   Wcat = (u16*)(ws + OFF_W);
    float* bias = (float*)(ws + OFF_BIAS);
    u16*   h0pp = (u16*)(ws + OFF_H0V);
    u16*   h1pp = (u16*)(ws + OFF_H0V + (size_t)2 * BH * 2);
    cvt_kernel<<<4096, 256, 0, stream>>>(Wih, Whh, bih, bhh, h0, input,
                                         Wcat, bias, h0pp + BH, h1pp + BH, nullptr);
    for (int t = 0; t <= T_STEPS; ++t)
      lstm_step<<<256, 256, 0, stream>>>(input, Wcat, bias, h0pp, h1pp, c0, out, t);
  } else {
    float* h0ppf = (float*)ws;
    float* h1ppf = (float*)(ws + (size_t)2 * BH * 4);
    fb_init<<<256, 256, 0, stream>>>(h0, h0ppf, h1ppf);
    for (int t = 0; t <= T_STEPS; ++t)
      fb_step<<<256, 256, 0, stream>>>(input, Wih, Whh, bih, bhh, h0ppf, h1ppf, c0, out, t);
  }
}

// Round 10
// 3239.631 us; speedup vs baseline: 1.9565x; 1.4629x over previous
//
#include <hip/hip_runtime.h>
#include <hip/hip_bf16.h>

// LSTM T=512 B=32 IN=H=1024 L=2. fp32 in/out, bf16 MFMA internally.
// Round 10: round 9 (epoch-aggregated flags + plain cached h loads) with the
// terminal-epoch deadlock fixed: after the loop, the l0 aggregator polls all
// l0 flags >= 512 and publishes EP0=512 so l1's final step can complete.

namespace {
constexpr int T_STEPS = 512;
constexpr int BATCH   = 32;
constexpr int HID     = 1024;
constexpr int G4H     = 4096;
constexpr int KCAT    = 2048;
constexpr int BH      = BATCH * HID;                 // 32768
constexpr size_t MEM_ELEMS = (size_t)T_STEPS * BH;   // 16,777,216

// workspace layout (bytes)
constexpr size_t OFF_W    = 0;
constexpr size_t SZ_W     = (size_t)2 * G4H * KCAT * 2;     // 33.55 MB bf16 W_cat
constexpr size_t OFF_BIAS = OFF_W + SZ_W;                   // f32 [2][4096]
constexpr size_t OFF_H0V  = OFF_BIAS + 32768;               // bf16 [513][32][1024]
constexpr size_t SZ_HV    = (size_t)(T_STEPS + 1) * BH * 2; // 33.62 MB
constexpr size_t OFF_H1V  = OFF_H0V + SZ_HV;
constexpr size_t OFF_FLAG = OFF_H1V + SZ_HV;                // u32[2][128]@16B + EP words
constexpr size_t SZ_FLAG  = 8192;
constexpr size_t OFF_X    = OFF_FLAG + SZ_FLAG;             // bf16 X [512][32][1024]
constexpr size_t WS_ASYNC = OFF_X + MEM_ELEMS * 2;          // ~135 MB
constexpr size_t WS_STEP  = OFF_H0V + (size_t)4 * BH * 2;   // tier-2: pp buffers only
}

typedef __attribute__((ext_vector_type(8))) short short8;
typedef __attribute__((ext_vector_type(4))) float f32x4;
typedef unsigned short u16;
typedef unsigned long long u64;

__device__ inline unsigned short f2bf(float x) {
  unsigned u = __builtin_bit_cast(unsigned, x);
  u += 0x7fffu + ((u >> 16) & 1u);          // RNE
  return (unsigned short)(u >> 16);
}
__device__ inline float sigm(float x) { return 1.0f / (1.0f + __expf(-x)); }

// ---------------- conversion: W_cat bf16, bias sum, initial h, X bf16 ----------------
__global__ void cvt_kernel(const float* __restrict__ Wih, const float* __restrict__ Whh,
                           const float* __restrict__ bih, const float* __restrict__ bhh,
                           const float* __restrict__ h0, const float* __restrict__ input,
                           u16* __restrict__ Wcat, float* __restrict__ bias,
                           u16* __restrict__ H0i, u16* __restrict__ H1i,
                           u16* __restrict__ Xbf) {
  size_t idx = (size_t)blockIdx.x * blockDim.x + threadIdx.x;
  size_t stride = (size_t)gridDim.x * blockDim.x;
  const size_t NW = (size_t)2 * G4H * KCAT;
  for (size_t i = idx; i < NW; i += stride) {
    size_t ln = i >> 11;                 // l*4096 + n
    int k = (int)(i & 2047);
    float v = (k < HID) ? Wih[ln * HID + k] : Whh[ln * HID + (k - HID)];
    Wcat[i] = f2bf(v);
  }
  for (size_t i = idx; i < (size_t)2 * G4H; i += stride) bias[i] = bih[i] + bhh[i];
  for (size_t i = idx; i < (size_t)2 * BH; i += stride) {
    unsigned short v = f2bf(h0[i]);
    if (i < (size_t)BH) H0i[i] = v;       // slot 0 = h at time 0
    else                H1i[i - BH] = v;
  }
  if (Xbf) {
    for (size_t i = idx; i < MEM_ELEMS; i += stride) Xbf[i] = f2bf(input[i]);
  }
}

// batched plain-cached loads for A fragments, then MFMA from registers + LDS B
__device__ __attribute__((always_inline)) void mfma_batched_pl(
    const unsigned char* smem, const u16* ab0, const u16* ab1,
    int kbyte_base, int xsw, int l15,
    f32x4& acc00, f32x4& acc01, f32x4& acc10, f32x4& acc11) {
  u64 ra0[16], ra1[16], rb0[16], rb1[16];
  #pragma unroll
  for (int ks = 0; ks < 16; ++ks) {
    const u64* q0 = (const u64*)(ab0 + ks * 32);
    const u64* q1 = (const u64*)(ab1 + ks * 32);
    ra0[ks] = q0[0]; ra1[ks] = q0[1];
    rb0[ks] = q1[0]; rb1[ks] = q1[1];
  }
  #pragma unroll
  for (int ks = 0; ks < 16; ++ks) {
    const int kb2 = kbyte_base + ks * 64;
    short8 b0 = *(const short8*)(smem + l15 * 4096 + (kb2 ^ xsw));
    short8 b1 = *(const short8*)(smem + (16 + l15) * 4096 + (kb2 ^ xsw));
    union { u64 u[2]; short8 s; } ua, ub;
    ua.u[0] = ra0[ks]; ua.u[1] = ra1[ks];
    ub.u[0] = rb0[ks]; ub.u[1] = rb1[ks];
    acc00 = __builtin_amdgcn_mfma_f32_16x16x32_bf16(ua.s, b0, acc00, 0, 0, 0);
    acc01 = __builtin_amdgcn_mfma_f32_16x16x32_bf16(ua.s, b1, acc01, 0, 0, 0);
    acc10 = __builtin_amdgcn_mfma_f32_16x16x32_bf16(ub.s, b0, acc10, 0, 0, 0);
    acc11 = __builtin_amdgcn_mfma_f32_16x16x32_bf16(ub.s, b1, acc11, 0, 0, 0);
  }
}

// ---------------- persistent free-running kernel ----------------
__global__ __launch_bounds__(256, 1) void lstm_async(
    const u16* __restrict__ Xbf, const u16* __restrict__ Wcat,
    const float* __restrict__ bias, u16* __restrict__ H0v, u16* __restrict__ H1v,
    const float* __restrict__ c0, float* __restrict__ out, unsigned* __restrict__ flags)
{
  // 128 KiB swizzled weights + 16 KiB reduction + 512 B h-stage + 64 B epochs
  __shared__ __align__(16) unsigned char smem[131072 + 16384 + 512 + 64];
  float* redf   = (float*)(smem + 131072);
  u16*   hstage = (u16*)(smem + 131072 + 16384);
  volatile unsigned* epl = (volatile unsigned*)(smem + 131072 + 16384 + 512);

  const bool is_l1 = (blockIdx.x >= 128);
  const int l  = is_l1 ? 1 : 0;
  const int cb = blockIdx.x & 127;
  const bool is_agg = (cb == 0);
  const int j0 = cb << 3;                  // 8 hidden units per block
  const int tid = threadIdx.x;
  const int lane = tid & 63;
  const int wid  = tid >> 6;
  const int l15  = lane & 15;
  const int lq   = lane >> 4;
  const int koff = lq << 3;
  const int k0   = wid << 9;               // wave K-slice: 512
  const int xsw  = (l15 & 7) << 4;         // LDS XOR swizzle for B reads
  const int kbyte_base = (k0 + koff) * 2;

  // ---- stage this block's 32 weight rows into LDS (XOR-swizzled) ----
  {
    const int kb = tid * 16;               // byte within a 4096B row
    for (int pr = 0; pr < 32; ++pr) {      // packed rows: [i x8][f x8][g x8][o x8]
      const u16* g = Wcat + ((size_t)l * G4H + (size_t)(pr >> 3) * HID + j0 + (pr & 7)) * KCAT;
      short8 v = *(const short8*)((const char*)g + kb);
      *(short8*)(smem + pr * 4096 + (kb ^ ((pr & 7) << 4))) = v;
    }
  }
  if (tid < 2) epl[tid] = 0;

  // elementwise mapping (one (m, jj) per thread)
  const int m  = tid >> 3;
  const int jj = tid & 7;
  const int j  = j0 + jj;
  const int mt = m >> 4;
  const int mm = m & 15;
  const int rr = mm & 3;
  const int lbase = (mm >> 2) << 4;
  float b4[4];
  #pragma unroll
  for (int g = 0; g < 4; ++g) b4[g] = bias[l * G4H + g * HID + j];

  float* hT = out + MEM_ELEMS;                      // [2][32][1024]
  float* cT = out + MEM_ELEMS + 2 * (size_t)BH;
  const size_t cidx = (size_t)l * BH + (size_t)m * HID + j;
  float c_reg = 0.f;
  u16* Hw = is_l1 ? H1v : H0v;
  unsigned* myflag = flags + (size_t)(l * 128 + cb) * 4;
  unsigned* EP0 = flags + 1024;     // byte 4096
  unsigned* EP1 = flags + 1040;     // byte 4160 (separate line)
  __syncthreads();

  for (int s = 0; s < T_STEPS; ++s) {
    // ---------- dependency wait (epoch-aggregated) ----------
    if (!is_l1) {
      if (wid == 2) {
        const unsigned need = (unsigned)s;
        if (need) {
          if (is_agg) {
            const unsigned* p0 = flags + lane * 4;
            const unsigned* p1 = flags + (lane + 64) * 4;
            for (;;) {
              unsigned a = __hip_atomic_load(p0, __ATOMIC_RELAXED, __HIP_MEMORY_SCOPE_AGENT);
              unsigned b = __hip_atomic_load(p1, __ATOMIC_RELAXED, __HIP_MEMORY_SCOPE_AGENT);
              if (__all((int)(a >= need && b >= need))) break;
              __builtin_amdgcn_s_sleep(2);
            }
            if (lane == 0)
              __hip_atomic_store(EP0, need, __ATOMIC_RELAXED, __HIP_MEMORY_SCOPE_AGENT);
          } else {
            while (__hip_atomic_load(EP0, __ATOMIC_RELAXED, __HIP_MEMORY_SCOPE_AGENT) < need)
              __builtin_amdgcn_s_sleep(2);
          }
          if (lane == 0) epl[0] = need;
        }
      } else if (wid == 3) {
        const unsigned need = (unsigned)s;
        while (epl[0] < need) __builtin_amdgcn_s_sleep(1);
      }
      // wid 0,1 (x-part): no wait
    } else {
      if (wid == 2) {
        const unsigned need = (unsigned)s;
        if (need) {
          if (is_agg) {
            const unsigned* p0 = flags + 512 + lane * 4;
            const unsigned* p1 = flags + 512 + (lane + 64) * 4;
            for (;;) {
              unsigned a = __hip_atomic_load(p0, __ATOMIC_RELAXED, __HIP_MEMORY_SCOPE_AGENT);
              unsigned b = __hip_atomic_load(p1, __ATOMIC_RELAXED, __HIP_MEMORY_SCOPE_AGENT);
              if (__all((int)(a >= need && b >= need))) break;
              __builtin_amdgcn_s_sleep(2);
            }
            if (lane == 0)
              __hip_atomic_store(EP1, need, __ATOMIC_RELAXED, __HIP_MEMORY_SCOPE_AGENT);
          } else {
            while (__hip_atomic_load(EP1, __ATOMIC_RELAXED, __HIP_MEMORY_SCOPE_AGENT) < need)
              __builtin_amdgcn_s_sleep(2);
          }
          if (lane == 0) epl[1] = need;
        }
      } else if (wid == 3) {
        const unsigned need0 = (unsigned)(s + 1);
        while (__hip_atomic_load(EP0, __ATOMIC_RELAXED, __HIP_MEMORY_SCOPE_AGENT) < need0)
          __builtin_amdgcn_s_sleep(2);
        if (lane == 0) epl[0] = need0;
        const unsigned need = (unsigned)s;
        while (epl[1] < need) __builtin_amdgcn_s_sleep(1);
      } else {  // wid 0,1 (x-part = h0[s+1])
        const unsigned need0 = (unsigned)(s + 1);
        while (epl[0] < need0) __builtin_amdgcn_s_sleep(1);
      }
    }
    asm volatile("" ::: "memory");   // keep h loads below the wait

    // ---------- source & MFMA (all plain cached loads) ----------
    const u16* src; int ksrc;
    if (!is_l1) {
      if (wid < 2) { src = Xbf + (size_t)s * BH;       ksrc = k0; }
      else         { src = H0v + (size_t)s * BH;       ksrc = k0 - HID; }
    } else {
      if (wid < 2) { src = H0v + (size_t)(s + 1) * BH; ksrc = k0; }
      else         { src = H1v + (size_t)s * BH;       ksrc = k0 - HID; }
    }
    const u16* ab0 = src + (size_t)l15 * HID + ksrc + koff;
    const u16* ab1 = src + (size_t)(16 + l15) * HID + ksrc + koff;
    f32x4 acc00 = {0.f, 0.f, 0.f, 0.f};
    f32x4 acc01 = acc00, acc10 = acc00, acc11 = acc00;
    mfma_batched_pl(smem, ab0, ab1, kbyte_base, xsw, l15, acc00, acc01, acc10, acc11);

    *(f32x4*)(redf + ((wid * 2 + 0) * 2 + 0) * 256 + lane * 4) = acc00;
    *(f32x4*)(redf + ((wid * 2 + 0) * 2 + 1) * 256 + lane * 4) = acc01;
    *(f32x4*)(redf + ((wid * 2 + 1) * 2 + 0) * 256 + lane * 4) = acc10;
    *(f32x4*)(redf + ((wid * 2 + 1) * 2 + 1) * 256 + lane * 4) = acc11;
    __syncthreads();   // A: accs staged

    float g4[4];
    #pragma unroll
    for (int gate = 0; gate < 4; ++gate) {
      const int nt = gate >> 1;
      const int nn = ((gate & 1) << 3) + jj;
      const int li = (lbase | nn) * 4 + rr;
      float v = redf[((0 * 2 + mt) * 2 + nt) * 256 + li] +
                redf[((1 * 2 + mt) * 2 + nt) * 256 + li] +
                redf[((2 * 2 + mt) * 2 + nt) * 256 + li] +
                redf[((3 * 2 + mt) * 2 + nt) * 256 + li];
      g4[gate] = v + b4[gate];
    }
    const float c_old = (s == 0) ? c0[cidx] : c_reg;
    const float ig = sigm(g4[0]);
    const float fg = sigm(g4[1]);
    const float gg = tanhf(g4[2]);
    const float og = sigm(g4[3]);
    const float c_new = fg * c_old + ig * gg;
    const float h_new = og * tanhf(c_new);
    c_reg = c_new;
    hstage[tid] = f2bf(h_new);
    if (is_l1) out[(size_t)s * BH + (size_t)m * HID + j] = h_new;
    if (s == T_STEPS - 1) { hT[cidx] = h_new; cT[cidx] = c_new; }
    __syncthreads();   // B: hstage ready, redf consumed

    // wave 3 publishes h chunk (write-through stores) + fires versioned flag
    if (wid == 3) {
      const int w2 = lane * 2;            // word-pair index in [0,128)
      unsigned lo0 = (unsigned)hstage[2 * w2]     | ((unsigned)hstage[2 * w2 + 1] << 16);
      unsigned lo1 = (unsigned)hstage[2 * w2 + 2] | ((unsigned)hstage[2 * w2 + 3] << 16);
      u64 v = (u64)lo0 | ((u64)lo1 << 32);
      const int mrow = w2 >> 2;           // lane>>1
      const int jp   = w2 & 3;            // {0,2}
      unsigned* b32 = (unsigned*)(Hw + (size_t)(s + 1) * BH);
      __hip_atomic_store((u64*)(b32 + mrow * 512 + (j0 >> 1) + jp), v,
                         __ATOMIC_RELAXED, __HIP_MEMORY_SCOPE_AGENT);
      asm volatile("s_waitcnt vmcnt(0)" ::: "memory");
      if (lane == 0)
        __hip_atomic_store(myflag, (unsigned)(s + 1),
                           __ATOMIC_RELAXED, __HIP_MEMORY_SCOPE_AGENT);
    }
  }

  // ---------- terminal epoch (r9 deadlock fix): l1's last step waits for
  // EP0 >= 512, but the loop only ever publishes up to 511. Aggregate the
  // final l0 flags here and publish EP0 = T_STEPS. ----------
  if (!is_l1 && is_agg && wid == 2) {
    const unsigned need = (unsigned)T_STEPS;
    const unsigned* p0 = flags + lane * 4;
    const unsigned* p1 = flags + (lane + 64) * 4;
    for (;;) {
      unsigned a = __hip_atomic_load(p0, __ATOMIC_RELAXED, __HIP_MEMORY_SCOPE_AGENT);
      unsigned b = __hip_atomic_load(p1, __ATOMIC_RELAXED, __HIP_MEMORY_SCOPE_AGENT);
      if (__all((int)(a >= need && b >= need))) break;
      __builtin_amdgcn_s_sleep(2);
    }
    if (lane == 0)
      __hip_atomic_store(EP0, need, __ATOMIC_RELAXED, __HIP_MEMORY_SCOPE_AGENT);
  }
}

// ---------------- tier-2: per-step launches (round-1, known-good) ----------------
__global__ __launch_bounds__(256) void lstm_step(
    const float* __restrict__ input, const u16* __restrict__ Wcat,
    const float* __restrict__ bias, u16* __restrict__ h0pp, u16* __restrict__ h1pp,
    const float* __restrict__ c0, float* __restrict__ out, int t)
{
  const bool is_l1 = (blockIdx.x >= 128);
  const int s = is_l1 ? (t - 1) : t;
  if (s < 0 || s >= T_STEPS) return;
  const int l = is_l1 ? 1 : 0;
  const int cb = blockIdx.x & 127;
  const int j0 = cb << 3;
  const int tid = threadIdx.x;
  const int lane = tid & 63;
  const int wid = tid >> 6;
  const int l15 = lane & 15;
  const int lq  = lane >> 4;
  const int koff = lq << 3;
  const int k0 = wid << 9;

  const int row0 = (l15 < 8) ? (j0 + l15) : (HID + j0 + l15 - 8);
  const int row1 = (l15 < 8) ? (2 * HID + j0 + l15) : (3 * HID + j0 + l15 - 8);
  const u16* bp0 = Wcat + ((size_t)l * G4H + row0) * KCAT + k0 + koff;
  const u16* bp1 = Wcat + ((size_t)l * G4H + row1) * KCAT + k0 + koff;

  f32x4 acc00 = {0.f, 0.f, 0.f, 0.f};
  f32x4 acc01 = acc00, acc10 = acc00, acc11 = acc00;

  const bool a_f32 = (!is_l1) && (wid < 2);
  if (a_f32) {
    const float* base = input + (size_t)s * BH + k0 + koff;
    const float* af0 = base + (size_t)l15 * HID;
    const float* af1 = base + (size_t)(16 + l15) * HID;
    #pragma unroll 4
    for (int ks = 0; ks < 16; ++ks) {
      const int kk = ks * 32;
      short8 b0 = *(const short8*)(bp0 + kk);
      short8 b1 = *(const short8*)(bp1 + kk);
      float4 x0 = *(const float4*)(af0 + kk);
      float4 x1 = *(const float4*)(af0 + kk + 4);
      float4 y0 = *(const float4*)(af1 + kk);
      float4 y1 = *(const float4*)(af1 + kk + 4);
      short8 a0, a1;
      a0[0] = (short)f2bf(x0.x); a0[1] = (short)f2bf(x0.y);
      a0[2] = (short)f2bf(x0.z); a0[3] = (short)f2bf(x0.w);
      a0[4] = (short)f2bf(x1.x); a0[5] = (short)f2bf(x1.y);
      a0[6] = (short)f2bf(x1.z); a0[7] = (short)f2bf(x1.w);
      a1[0] = (short)f2bf(y0.x); a1[1] = (short)f2bf(y0.y);
      a1[2] = (short)f2bf(y0.z); a1[3] = (short)f2bf(y0.w);
      a1[4] = (short)f2bf(y1.x); a1[5] = (short)f2bf(y1.y);
      a1[6] = (short)f2bf(y1.z); a1[7] = (short)f2bf(y1.w);
      acc00 = __builtin_amdgcn_mfma_f32_16x16x32_bf16(a0, b0, acc00, 0, 0, 0);
      acc01 = __builtin_amdgcn_mfma_f32_16x16x32_bf16(a0, b1, acc01, 0, 0, 0);
      acc10 = __builtin_amdgcn_mfma_f32_16x16x32_bf16(a1, b0, acc10, 0, 0, 0);
      acc11 = __builtin_amdgcn_mfma_f32_16x16x32_bf16(a1, b1, acc11, 0, 0, 0);
    }
  } else {
    const u16* src; int ksrc;
    if (!is_l1)       { src = h0pp + (size_t)(((s + 1) & 1)) * BH; ksrc = k0 - HID; }
    else if (wid < 2) { src = h0pp + (size_t)((s & 1)) * BH;       ksrc = k0;       }
    else              { src = h1pp + (size_t)(((s + 1) & 1)) * BH; ksrc = k0 - HID; }
    const u16* ab0 = src + (size_t)l15 * HID + ksrc + koff;
    const u16* ab1 = src + (size_t)(16 + l15) * HID + ksrc + koff;
    #pragma unroll 4
    for (int ks = 0; ks < 16; ++ks) {
      const int kk = ks * 32;
      short8 b0 = *(const short8*)(bp0 + kk);
      short8 b1 = *(const short8*)(bp1 + kk);
      short8 a0 = *(const short8*)(ab0 + kk);
      short8 a1 = *(const short8*)(ab1 + kk);
      acc00 = __builtin_amdgcn_mfma_f32_16x16x32_bf16(a0, b0, acc00, 0, 0, 0);
      acc01 = __builtin_amdgcn_mfma_f32_16x16x32_bf16(a0, b1, acc01, 0, 0, 0);
      acc10 = __builtin_amdgcn_mfma_f32_16x16x32_bf16(a1, b0, acc10, 0, 0, 0);
      acc11 = __builtin_amdgcn_mfma_f32_16x16x32_bf16(a1, b1, acc11, 0, 0, 0);
    }
  }

  __shared__ float red[4][2][2][256];
  #pragma unroll
  for (int r = 0; r < 4; ++r) {
    red[wid][0][0][lane * 4 + r] = acc00[r];
    red[wid][0][1][lane * 4 + r] = acc01[r];
    red[wid][1][0][lane * 4 + r] = acc10[r];
    red[wid][1][1][lane * 4 + r] = acc11[r];
  }
  __syncthreads();

  const int m  = tid >> 3;
  const int jj = tid & 7;
  const int j  = j0 + jj;
  const int mt = m >> 4;
  const int mm = m & 15;
  const int rr = mm & 3;
  const int lbase = (mm >> 2) << 4;

  float g4[4];
  #pragma unroll
  for (int gate = 0; gate < 4; ++gate) {
    const int nt = gate >> 1;
    const int nn = ((gate & 1) << 3) + jj;
    const int li = (lbase | nn) * 4 + rr;
    float v = red[0][mt][nt][li] + red[1][mt][nt][li] +
              red[2][mt][nt][li] + red[3][mt][nt][li];
    g4[gate] = v + bias[l * G4H + gate * HID + j];
  }

  float* hT     = out + MEM_ELEMS;
  float* cstate = out + MEM_ELEMS + 2 * (size_t)BH;
  const size_t cidx = (size_t)l * BH + (size_t)m * HID + j;
  const float c_old = (s == 0) ? c0[cidx] : cstate[cidx];
  const float ig = sigm(g4[0]);
  const float fg = sigm(g4[1]);
  const float gg = tanhf(g4[2]);
  const float og = sigm(g4[3]);
  const float c_new = fg * c_old + ig * gg;
  const float h_new = og * tanhf(c_new);
  cstate[cidx] = c_new;
  u16* ppw = (is_l1 ? h1pp : h0pp) + (size_t)(s & 1) * BH;
  ppw[m * HID + j] = f2bf(h_new);
  if (is_l1) out[(size_t)s * BH + (size_t)m * HID + j] = h_new;
  if (s == T_STEPS - 1) hT[cidx] = h_new;
}

// ---------------- tier-3: fp32 fallback ----------------
__global__ void fb_init(const float* __restrict__ h0, float* __restrict__ h0ppf,
                        float* __restrict__ h1ppf) {
  int i = blockIdx.x * blockDim.x + threadIdx.x;
  if (i < BH) h0ppf[BH + i] = h0[i];
  else if (i < 2 * BH) h1ppf[BH + (i - BH)] = h0[i];
}

__global__ __launch_bounds__(256) void fb_step(
    const float* __restrict__ input, const float* __restrict__ Wih,
    const float* __restrict__ Whh, const float* __restrict__ bih,
    const float* __restrict__ bhh, float* __restrict__ h0ppf, float* __restrict__ h1ppf,
    const float* __restrict__ c0, float* __restrict__ out, int t)
{
  const bool is_l1 = (blockIdx.x >= 128);
  const int s = is_l1 ? (t - 1) : t;
  if (s < 0 || s >= T_STEPS) return;
  const int l = is_l1 ? 1 : 0;
  const int cb = blockIdx.x & 127, j0 = cb << 3, tid = threadIdx.x;
  const float* xsrc = is_l1 ? (h0ppf + (size_t)(s & 1) * BH) : (input + (size_t)s * BH);
  const float* hsrc = (is_l1 ? h1ppf : h0ppf) + (size_t)((s + 1) & 1) * BH;
  const int c = tid & 31, mg = tid >> 5;
  const int gate = c >> 3, jc = c & 7;
  const int row = gate * HID + j0 + jc;
  const float* wi = Wih + ((size_t)l * G4H + row) * HID;
  const float* wh = Whh + ((size_t)l * G4H + row) * HID;
  float a0 = 0, a1 = 0, a2 = 0, a3 = 0;
  const float* x0 = xsrc + (size_t)(mg * 4 + 0) * HID;
  const float* x1 = xsrc + (size_t)(mg * 4 + 1) * HID;
  const float* x2 = xsrc + (size_t)(mg * 4 + 2) * HID;
  const float* x3 = xsrc + (size_t)(mg * 4 + 3) * HID;
  const float* h0p = hsrc + (size_t)(mg * 4 + 0) * HID;
  const float* h1p = hsrc + (size_t)(mg * 4 + 1) * HID;
  const float* h2p = hsrc + (size_t)(mg * 4 + 2) * HID;
  const float* h3p = hsrc + (size_t)(mg * 4 + 3) * HID;
  for (int k = 0; k < HID; ++k) {
    float wa = wi[k], wb = wh[k];
    a0 += x0[k] * wa + h0p[k] * wb;
    a1 += x1[k] * wa + h1p[k] * wb;
    a2 += x2[k] * wa + h2p[k] * wb;
    a3 += x3[k] * wa + h3p[k] * wb;
  }
  __shared__ float gl[32][32];
  const float bsum = bih[l * G4H + row] + bhh[l * G4H + row];
  gl[mg * 4 + 0][c] = a0 + bsum;
  gl[mg * 4 + 1][c] = a1 + bsum;
  gl[mg * 4 + 2][c] = a2 + bsum;
  gl[mg * 4 + 3][c] = a3 + bsum;
  __syncthreads();
  const int m = tid >> 3, jj = tid & 7, j = j0 + jj;
  float g4[4];
  #pragma unroll
  for (int g = 0; g < 4; ++g) g4[g] = gl[m][g * 8 + jj];
  float* hT = out + MEM_ELEMS;
  float* cstate = out + MEM_ELEMS + 2 * (size_t)BH;
  const size_t cidx = (size_t)l * BH + (size_t)m * HID + j;
  const float c_old = (s == 0) ? c0[cidx] : cstate[cidx];
  const float ig = sigm(g4[0]);
  const float fg = sigm(g4[1]);
  const float gg = tanhf(g4[2]);
  const float og = sigm(g4[3]);
  const float c_new = fg * c_old + ig * gg;
  const float h_new = og * tanhf(c_new);
  cstate[cidx] = c_new;
  float* ppw = (is_l1 ? h1ppf : h0ppf) + (size_t)(s & 1) * BH;
  ppw[m * HID + j] = h_new;
  if (is_l1) out[(size_t)s * BH + (size_t)m * HID + j] = h_new;
  if (s == T_STEPS - 1) hT[cidx] = h_new;
}

extern "C" void kernel_launch(void* const* d_in, const int* in_sizes, int n_in,
                              void* d_out, int out_size, void* d_ws, size_t ws_size,
                              hipStream_t stream) {
  const float* input = (const float*)d_in[0];
  const float* h0    = (const float*)d_in[1];
  const float* c0    = (const float*)d_in[2];
  const float* Wih   = (const float*)d_in[3];
  const float* Whh   = (const float*)d_in[4];
  const float* bih   = (const float*)d_in[5];
  const float* bhh   = (const float*)d_in[6];
  float* out = (float*)d_out;
  char* ws = (char*)d_ws;

  if (ws_size >= WS_ASYNC) {
    u16*   Wcat = (u16*)(ws + OFF_W);
    float* bias = (float*)(ws + OFF_BIAS);
    u16*   H0v  = (u16*)(ws + OFF_H0V);
    u16*   H1v  = (u16*)(ws + OFF_H1V);
    unsigned* flags = (unsigned*)(ws + OFF_FLAG);
    u16*   Xbf  = (u16*)(ws + OFF_X);

    int occ = 0;   // all 256 blocks must be co-resident for free-running flags
    (void)hipOccupancyMaxActiveBlocksPerMultiprocessor(&occ, lstm_async, 256, 0);
    if (occ >= 1) {
      cvt_kernel<<<4096, 256, 0, stream>>>(Wih, Whh, bih, bhh, h0, input,
                                           Wcat, bias, H0v, H1v, Xbf);
      hipMemsetAsync(ws + OFF_FLAG, 0, SZ_FLAG, stream);
      lstm_async<<<256, 256, 0, stream>>>(Xbf, Wcat, bias, H0v, H1v, c0, out, flags);
      return;
    }
  }
  if (ws_size >= WS_STEP) {
    u16*   Wcat = (u16*)(ws + OFF_W);
    float* bias = (float*)(ws + OFF_BIAS);
    u16*   h0pp = (u16*)(ws + OFF_H0V);
    u16*   h1pp = (u16*)(ws + OFF_H0V + (size_t)2 * BH * 2);
    cvt_kernel<<<4096, 256, 0, stream>>>(Wih, Whh, bih, bhh, h0, input,
                                         Wcat, bias, h0pp + BH, h1pp + BH, nullptr);
    for (int t = 0; t <= T_STEPS; ++t)
      lstm_step<<<256, 256, 0, stream>>>(input, Wcat, bias, h0pp, h1pp, c0, out, t);
  } else {
    float* h0ppf = (float*)ws;
    float* h1ppf = (float*)(ws + (size_t)2 * BH * 4);
    fb_init<<<256, 256, 0, stream>>>(h0, h0ppf, h1ppf);
    for (int t = 0; t <= T_STEPS; ++t)
      fb_step<<<256, 256, 0, stream>>>(input, Wih, Whh, bih, bhh, h0ppf, h1ppf, c0, out, t);
  }
}